// Round 12
// baseline (6425.802 us; speedup 1.0000x reference)
//
#include <hip/hip_runtime.h>
#include <hip/hip_bf16.h>

#define BB 32
#define KK 2048
#define NTOK 2049
#define DD 512
#define NH 8
#define DHD 64
#define NL 4
#define MM 256
#define RTOT (BB*NTOK)          // 65568
#define QROWS (RTOT/4)          // 16392
#define DN 0.35355339059327373f // 64^-0.25
#define RM 0.0625f              // 256^-0.5
#define EPSK 1e-4f

typedef __attribute__((ext_vector_type(8))) short bf16x8;
typedef __attribute__((ext_vector_type(4))) float f32x4;

__device__ __forceinline__ float wsum(float v) {
#pragma unroll
  for (int o = 32; o; o >>= 1) v += __shfl_xor(v, o);
  return v;
}
__device__ __forceinline__ float wmax(float v) {
#pragma unroll
  for (int o = 32; o; o >>= 1) v = fmaxf(v, __shfl_xor(v, o));
  return v;
}
__device__ __forceinline__ float gelu1(float v) {
  return 0.5f * v * (1.0f + erff(v * 0.70710678118654752f));
}
__device__ __forceinline__ float b2f(unsigned short u) {
  union { unsigned int i; float f; } w; w.i = ((unsigned int)u) << 16; return w.f;
}
__device__ __forceinline__ unsigned short f2b(float f) {
  union { float f; unsigned int i; } w; w.f = f;
  unsigned int r = w.i + 0x7FFFu + ((w.i >> 16) & 1u);
  return (unsigned short)(r >> 16);
}
__device__ __forceinline__ float4 ld4(const float* p) { return *(const float4*)p; }
__device__ __forceinline__ float4 ld4(const unsigned short* p) {
  ushort4 u = *(const ushort4*)p;
  return make_float4(b2f(u.x), b2f(u.y), b2f(u.z), b2f(u.w));
}
__device__ __forceinline__ void st4(float* p, float4 v) { *(float4*)p = v; }
__device__ __forceinline__ void st4(unsigned short* p, float4 v) {
  ushort4 u; u.x = f2b(v.x); u.y = f2b(v.y); u.z = f2b(v.z); u.w = f2b(v.w);
  *(ushort4*)p = u;
}
// bf16x8 from two 8B LDS loads (rows only 8B-aligned)
__device__ __forceinline__ bf16x8 ld8s(const unsigned short* p) {
  union { ushort4 u[2]; bf16x8 v; } w;
  w.u[0] = *(const ushort4*)p;
  w.u[1] = *(const ushort4*)(p + 4);
  return w.v;
}
__device__ __forceinline__ void gload16(const void* g, void* l) {
  __builtin_amdgcn_global_load_lds(
      (const __attribute__((address_space(1))) void*)g,
      (__attribute__((address_space(3))) void*)l, 16, 0, 0);
}

// ---------------- sentinel: ws too small -> absmax ~1.2e4 ----------------
__global__ void sentinel_k(float* out, int n) {
  int i = blockIdx.x * 256 + threadIdx.x;
  if (i < n) out[i] = 12345.0f;
}

// ---------------- weight convert + transpose: Wt[n][k] = bf16(W[k][n]) ----------------
__global__ __launch_bounds__(256) void wcvt_k(const float* __restrict__ W,
    unsigned short* __restrict__ Wt, int Kd, int Cols) {
  __shared__ float Ls[64][65];
  int tid = threadIdx.x;
  int n0 = blockIdx.x * 64, k0 = blockIdx.y * 64;
  int kr = tid >> 2, nseg = (tid & 3) << 4;
#pragma unroll
  for (int u = 0; u < 4; ++u) {
    float4 v = *(const float4*)(W + (size_t)(k0 + kr) * Cols + n0 + nseg + u * 4);
    *(float4*)&Ls[kr][nseg + u * 4] = v;
  }
  __syncthreads();
  int nr = tid >> 2, kseg = (tid & 3) << 4;
  unsigned int pk[8];
#pragma unroll
  for (int i = 0; i < 8; ++i) {
    unsigned short lo = f2b(Ls[kseg + 2 * i][nr]);
    unsigned short hi = f2b(Ls[kseg + 2 * i + 1][nr]);
    pk[i] = (unsigned int)lo | ((unsigned int)hi << 16);
  }
  unsigned short* dst = Wt + (size_t)(n0 + nr) * Kd + k0 + kseg;
  ((uint4*)dst)[0] = make_uint4(pk[0], pk[1], pk[2], pk[3]);
  ((uint4*)dst)[1] = make_uint4(pk[4], pk[5], pk[6], pk[7]);
}

// ---------------- embedding ----------------
__global__ __launch_bounds__(256) void embed_k(const float* __restrict__ expr,
    const int* __restrict__ gene_ids, const float* __restrict__ gene_table,
    const float* __restrict__ pos_table, const float* __restrict__ value_tab,
    float* __restrict__ x) {
  int tok = blockIdx.x * 2 + (threadIdx.x >> 7);
  int t = threadIdx.x & 127;
  int b = tok >> 11;
  int k = tok & 2047;
  float e = expr[tok];
  int bin = (int)(e * 5.0f);
  bin = bin < 0 ? 0 : (bin > 4 ? 4 : bin);
  int g = gene_ids[k];
  float4 a = ((const float4*)(gene_table + (size_t)g * DD))[t];
  float4 p = ((const float4*)(pos_table + (size_t)k * DD))[t];
  float4 vv = ((const float4*)(value_tab + (size_t)bin * DD))[t];
  float4 r;
  r.x = a.x + p.x + vv.x; r.y = a.y + p.y + vv.y;
  r.z = a.z + p.z + vv.z; r.w = a.w + p.w + vv.w;
  ((float4*)(x + ((size_t)b * NTOK + 1 + k) * DD))[t] = r;
}

// ---------------- spatial token ----------------
__global__ __launch_bounds__(256) void sp_k(const float* __restrict__ coords,
    const float* __restrict__ sp_w, const float* __restrict__ sp_b,
    const float* __restrict__ g, const float* __restrict__ bb,
    float* __restrict__ x) {
  int b = blockIdx.x, t = threadIdx.x;
  __shared__ float red[8];
  float c0 = coords[2 * b], c1 = coords[2 * b + 1];
  float v0 = fmaf(c0, sp_w[t],       fmaf(c1, sp_w[512 + t], sp_b[t]));
  float v1 = fmaf(c0, sp_w[t + 256], fmaf(c1, sp_w[768 + t], sp_b[t + 256]));
  float s = wsum(v0 + v1);
  int wid = t >> 6;
  if ((t & 63) == 0) red[wid] = s;
  __syncthreads();
  float mu = (red[0] + red[1] + red[2] + red[3]) * (1.0f / 512.0f);
  float d0 = v0 - mu, d1 = v1 - mu;
  float s2 = wsum(d0 * d0 + d1 * d1);
  if ((t & 63) == 0) red[4 + wid] = s2;
  __syncthreads();
  float var = (red[4] + red[5] + red[6] + red[7]) * (1.0f / 512.0f);
  float rs = rsqrtf(var + 1e-5f);
  float y0 = d0 * rs * g[t] + bb[t];
  float y1 = d1 * rs * g[t + 256] + bb[t + 256];
  x[(size_t)b * NTOK * DD + t] = gelu1(y0);
  x[(size_t)b * NTOK * DD + t + 256] = gelu1(y1);
}

// ---------------- fused LN -> bf16 ----------------
__global__ __launch_bounds__(128) void ln_k(const float* __restrict__ x,
    const float* __restrict__ gamma, const float* __restrict__ beta,
    unsigned short* __restrict__ h) {
  size_t row = blockIdx.x;
  int t = threadIdx.x;
  float4 v = ((const float4*)(x + row * DD))[t];
  float s = v.x + v.y + v.z + v.w;
  float s2 = v.x * v.x + v.y * v.y + v.z * v.z + v.w * v.w;
  __shared__ float red[4];
  float ws1 = wsum(s), ws2 = wsum(s2);
  int wid = t >> 6;
  if ((t & 63) == 0) { red[wid * 2] = ws1; red[wid * 2 + 1] = ws2; }
  __syncthreads();
  float S = red[0] + red[2], S2 = red[1] + red[3];
  float mu = S * (1.0f / 512.0f);
  float var = S2 * (1.0f / 512.0f) - mu * mu;
  float rs = rsqrtf(var + 1e-5f);
  float4 gm = ((const float4*)gamma)[t], bt = ((const float4*)beta)[t];
  float4 o;
  o.x = (v.x - mu) * rs * gm.x + bt.x;
  o.y = (v.y - mu) * rs * gm.y + bt.y;
  o.z = (v.z - mu) * rs * gm.z + bt.z;
  o.w = (v.w - mu) * rs * gm.w + bt.w;
  st4(h + row * DD + t * 4, o);
}

// ---------------- fp32 -> bf16 convert ----------------
__global__ __launch_bounds__(256) void cvt_k(const float* __restrict__ x,
    unsigned short* __restrict__ o, size_t n8) {
  size_t i = (size_t)blockIdx.x * 256 + threadIdx.x;
  if (i >= n8) return;
  float4 a = ((const float4*)x)[2 * i];
  float4 b = ((const float4*)x)[2 * i + 1];
  st4(o + i * 8, a);
  st4(o + i * 8 + 4, b);
}

// ======= all-bf16 MFMA GEMM, BK=64 + XOR-swizzled LDS + bijective XCD swizzle =======
template <typename TC, int FLAGS>
__global__ __launch_bounds__(256) void gemm_bb(const unsigned short* __restrict__ A, long lda,
    const unsigned short* __restrict__ Wt, const float* __restrict__ bias,
    TC* __restrict__ C, int ldc, int R, int Kd) {
  __shared__ unsigned short As[128 * 64];
  __shared__ unsigned short Bs[128 * 64];
  const int tid = threadIdx.x;
  const int lane = tid & 63;
  const int w = tid >> 6;
  const int wr = w >> 1, wc = w & 1;
  // XCD-aware bijective remap (m204): each XCD owns a contiguous logical chunk
  const int nwg = gridDim.x * gridDim.y;
  const int orig = blockIdx.y * gridDim.x + blockIdx.x;
  const int qd = nwg >> 3, rm = nwg & 7;
  const int xcd = orig & 7, idx = orig >> 3;
  const int wg = (xcd < rm ? xcd * (qd + 1) : rm * (qd + 1) + (xcd - rm) * qd) + idx;
  const int rblk = (wg / gridDim.x) << 7;
  const int cblk = (wg % gridDim.x) << 7;
  const int m0 = lane & 15, kb = lane >> 4;
  const int lrow8 = lane >> 3;
  const int csw = (((lane & 7) ^ lrow8) << 3);
  f32x4 acc[4][4] = {};
  for (int k0 = 0; k0 < Kd; k0 += 64) {
#pragma unroll
    for (int rd = 0; rd < 4; ++rd) {
      int rg = w * 32 + rd * 8;
      int gra = rblk + rg + lrow8; if (gra >= R) gra = R - 1;
      gload16(A  + (size_t)gra * lda + k0 + csw, &As[rg * 64]);
      gload16(Wt + (size_t)(cblk + rg + lrow8) * Kd + k0 + csw, &Bs[rg * 64]);
    }
    __syncthreads();
    bf16x8 af[2][4], bfr[2][4];
#pragma unroll
    for (int ks = 0; ks < 2; ++ks) {
      int c = (ks << 2) | kb;
#pragma unroll
      for (int mi = 0; mi < 4; ++mi) {
        int ar = wr * 64 + mi * 16 + m0;
        af[ks][mi] = *(const bf16x8*)&As[ar * 64 + ((c ^ (ar & 7)) << 3)];
        int br = wc * 64 + mi * 16 + m0;
        bfr[ks][mi] = *(const bf16x8*)&Bs[br * 64 + ((c ^ (br & 7)) << 3)];
      }
    }
#pragma unroll
    for (int ks = 0; ks < 2; ++ks)
#pragma unroll
      for (int mi = 0; mi < 4; ++mi)
#pragma unroll
        for (int ni = 0; ni < 4; ++ni)
          acc[mi][ni] = __builtin_amdgcn_mfma_f32_16x16x32_bf16(af[ks][mi], bfr[ks][ni], acc[mi][ni], 0, 0, 0);
    __syncthreads();
  }
  const int lrow4 = (lane >> 4) << 2, lcol = lane & 15;
#pragma unroll
  for (int mi = 0; mi < 4; ++mi) {
#pragma unroll
    for (int reg = 0; reg < 4; ++reg) {
      int row = rblk + wr * 64 + mi * 16 + lrow4 + reg;
      if (row < R) {
#pragma unroll
        for (int ni = 0; ni < 4; ++ni) {
          int col = cblk + wc * 64 + ni * 16 + lcol;
          float v = acc[mi][ni][reg] + bias[col];
          if constexpr ((FLAGS & 1) != 0) v = gelu1(v);
          if constexpr (sizeof(TC) == 4) {
            float* cp = (float*)C + (size_t)row * ldc + col;
            if constexpr ((FLAGS & 2) != 0) v += *cp;
            *cp = v;
          } else {
            unsigned short* cp = (unsigned short*)C + (size_t)row * ldc + col;
            if constexpr ((FLAGS & 2) != 0) v += b2f(*cp);
            *cp = f2b(v);
          }
        }
      }
    }
  }
}

// ---------------- fp32 tile GEMM (tiny qc only) ----------------
template <typename TA, typename TC>
__global__ __launch_bounds__(256) void gemm_t(const TA* __restrict__ A, long lda,
    const float* __restrict__ W, const float* __restrict__ bias,
    TC* __restrict__ C, int ldc, int R, int Kd, int Cols) {
  __shared__ float As[16][68];
  __shared__ float Ws[16][64];
  int tid = threadIdx.x;
  int tx = tid & 15, ty = tid >> 4;
  int rblk = blockIdx.y << 6, cblk = blockIdx.x << 6;
  float acc[4][4] = {};
  int lr = tid >> 2, lk = (tid & 3) << 2;
  int wk = tid >> 4, wcc = (tid & 15) << 2;
  int gra = rblk + lr;
  for (int k0 = 0; k0 < Kd; k0 += 16) {
    float4 av = make_float4(0.f, 0.f, 0.f, 0.f);
    if (gra < R) av = ld4(A + (size_t)gra * lda + k0 + lk);
    As[lk][lr] = av.x; As[lk + 1][lr] = av.y; As[lk + 2][lr] = av.z; As[lk + 3][lr] = av.w;
    *(float4*)&Ws[wk][wcc] = *(const float4*)(W + (size_t)(k0 + wk) * Cols + cblk + wcc);
    __syncthreads();
#pragma unroll
    for (int p = 0; p < 16; ++p) {
      float4 a4 = *(const float4*)&As[p][ty << 2];
      float4 b4 = *(const float4*)&Ws[p][tx << 2];
      acc[0][0] = fmaf(a4.x, b4.x, acc[0][0]); acc[0][1] = fmaf(a4.x, b4.y, acc[0][1]);
      acc[0][2] = fmaf(a4.x, b4.z, acc[0][2]); acc[0][3] = fmaf(a4.x, b4.w, acc[0][3]);
      acc[1][0] = fmaf(a4.y, b4.x, acc[1][0]); acc[1][1] = fmaf(a4.y, b4.y, acc[1][1]);
      acc[1][2] = fmaf(a4.y, b4.z, acc[1][2]); acc[1][3] = fmaf(a4.y, b4.w, acc[1][3]);
      acc[2][0] = fmaf(a4.z, b4.x, acc[2][0]); acc[2][1] = fmaf(a4.z, b4.y, acc[2][1]);
      acc[2][2] = fmaf(a4.z, b4.z, acc[2][2]); acc[2][3] = fmaf(a4.z, b4.w, acc[2][3]);
      acc[3][0] = fmaf(a4.w, b4.x, acc[3][0]); acc[3][1] = fmaf(a4.w, b4.y, acc[3][1]);
      acc[3][2] = fmaf(a4.w, b4.z, acc[3][2]); acc[3][3] = fmaf(a4.w, b4.w, acc[3][3]);
    }
    __syncthreads();
  }
  int gcb = cblk + (tx << 2);
  float4 bi = *(const float4*)(bias + gcb);
#pragma unroll
  for (int i = 0; i < 4; ++i) {
    int gr = rblk + (ty << 2) + i;
    if (gr < R) {
      float4 val;
      val.x = acc[i][0] + bi.x; val.y = acc[i][1] + bi.y;
      val.z = acc[i][2] + bi.z; val.w = acc[i][3] + bi.w;
      TC* cp = C + (size_t)gr * ldc + gcb;
      st4(cp, val);
    }
  }
}

// ------- FAVOR key pass 1 (MFMA, XCD-swizzled): max over dd = K@proj^T -------
__global__ __launch_bounds__(256) void kmax_k(const unsigned short* __restrict__ kq,
    const unsigned short* __restrict__ projb, float* __restrict__ bmax) {
  int orig = blockIdx.y * gridDim.x + blockIdx.x;   // grid (256,4) = 1024
  int wg = ((orig & 7) << 7) + (orig >> 3);
  int bh = wg >> 2, gy = wg & 3;
  int b = bh >> 3, hh = bh & 7;
  int tid = threadIdx.x;
  int lane = tid & 63, w = tid >> 6;
  int m0 = lane & 15, kb = lane >> 4;
  __shared__ float red[4];
  bf16x8 bp[4][2];
#pragma unroll
  for (int nf = 0; nf < 4; ++nf)
#pragma unroll
    for (int ks = 0; ks < 2; ++ks)
      bp[nf][ks] = *(const bf16x8*)(projb + (size_t)(w * 64 + nf * 16 + m0) * 64 + ks * 32 + kb * 8);
  float mx = -1e30f;
  for (int t = gy; t < 65; t += 4) {
    int n0 = t * 32;
    bf16x8 aq[2][2];
#pragma unroll
    for (int mi = 0; mi < 2; ++mi) {
      int n = n0 + mi * 16 + m0; if (n >= NTOK) n = NTOK - 1;  // dup valid token: max-safe
#pragma unroll
      for (int ks = 0; ks < 2; ++ks)
        aq[mi][ks] = *(const bf16x8*)(kq + ((size_t)b * NTOK + n) * DD + hh * DHD + ks * 32 + kb * 8);
    }
    f32x4 da[2][4] = {};
#pragma unroll
    for (int ks = 0; ks < 2; ++ks)
#pragma unroll
      for (int mi = 0; mi < 2; ++mi)
#pragma unroll
        for (int nf = 0; nf < 4; ++nf)
          da[mi][nf] = __builtin_amdgcn_mfma_f32_16x16x32_bf16(aq[mi][ks], bp[nf][ks], da[mi][nf], 0, 0, 0);
#pragma unroll
    for (int mi = 0; mi < 2; ++mi)
#pragma unroll
      for (int nf = 0; nf < 4; ++nf)
#pragma unroll
        for (int r = 0; r < 4; ++r)
          mx = fmaxf(mx, da[mi][nf][r]);
  }
  mx *= DN;
  mx = wmax(mx);
  if ((tid & 63) == 0) red[tid >> 6] = mx;
  __syncthreads();
  if (tid == 0)
    bmax[(size_t)bh * 4 + gy] = fmaxf(fmaxf(red[0], red[1]), fmaxf(red[2], red[3]));
}

__global__ __launch_bounds__(256) void maxred_k(const float* __restrict__ in, int n,
                                                float* __restrict__ out) {
  float m = -1e30f;
  for (int i = threadIdx.x; i < n; i += 256) m = fmaxf(m, in[i]);
  m = wmax(m);
  __shared__ float red[4];
  if ((threadIdx.x & 63) == 0) red[threadIdx.x >> 6] = m;
  __syncthreads();
  if (threadIdx.x == 0) out[0] = fmaxf(fmaxf(red[0], red[1]), fmaxf(red[2], red[3]));
}

// ===== FAVOR key pass 2 v5 (MFMA, feature-split, conflict-reduced LDS) =====
__global__ __launch_bounds__(256) void k2_k(const unsigned short* __restrict__ kq,
    const unsigned short* __restrict__ vv, const unsigned short* __restrict__ projb,
    const float* __restrict__ kmaxg, unsigned short* __restrict__ ctxTb,
    float* __restrict__ kpsum) {
  int orig = blockIdx.y * gridDim.x + blockIdx.x;   // grid (256,4) = 1024
  int wg = ((orig & 7) << 7) + (orig >> 3);
  int bh = wg >> 2, mg = wg & 3;
  int b = bh >> 3, hh = bh & 7;
  int tid = threadIdx.x;
  int lane = tid & 63, w = tid >> 6;
  int m0 = lane & 15, kb = lane >> 4;
  __shared__ __align__(16) float ddl[32 * 74];            // stride 74: kb-banks distinct
  __shared__ __align__(16) unsigned short kpT[64 * 44];   // stride 44: ~4-way worst
  __shared__ __align__(16) unsigned short VT[64 * 44];
  __shared__ float diag_s[32];
  __shared__ float ksum_lds[256];
  float kmax = kmaxg[0];
  bf16x8 bp[2];
#pragma unroll
  for (int ks = 0; ks < 2; ++ks)
    bp[ks] = *(const bf16x8*)(projb + (size_t)(mg * 64 + w * 16 + m0) * 64 + ks * 32 + kb * 8);
  f32x4 acc[4] = {};
  float ksum = 0.f;
  int fl = tid & 63, q = tid >> 6;       // exp phase: feature, token-quarter
  int dv = tid & 63, tq = tid >> 6;      // V^T staging: dim, token-quarter
  for (int t = 0; t < 65; ++t) {
    int n0 = t * 32;
    int tlim = NTOK - n0; if (tlim > 32) tlim = 32;
    __syncthreads();
    // ---- stage V^T: thread (dv, tq) packs 8 tokens of dim dv (coalesced reads) ----
    {
      unsigned int pk[4];
#pragma unroll
      for (int j = 0; j < 8; ++j) {
        int n = n0 + tq * 8 + j; if (n >= NTOK) n = NTOK - 1;
        unsigned int v = vv[((size_t)b * NTOK + n) * DD + hh * DHD + dv];
        if (j & 1) pk[j >> 1] |= v << 16; else pk[j >> 1] = v;
      }
      *(uint2*)&VT[dv * 44 + tq * 8]     = make_uint2(pk[0], pk[1]);
      *(uint2*)&VT[dv * 44 + tq * 8 + 4] = make_uint2(pk[2], pk[3]);
    }
    // ---- dd MFMA: A = K token rows (global), B = bp ----
    bf16x8 aq[2][2];
#pragma unroll
    for (int mi = 0; mi < 2; ++mi) {
      int n = n0 + mi * 16 + m0; if (n >= NTOK) n = NTOK - 1;
#pragma unroll
      for (int ks = 0; ks < 2; ++ks)
        aq[mi][ks] = *(const bf16x8*)(kq + ((size_t)b * NTOK + n) * DD + hh * DHD + ks * 32 + kb * 8);
    }
    if (w == 0) {
#pragma unroll
      for (int mi = 0; mi < 2; ++mi) {
        float s = 0.f;
        const unsigned short* ap = (const unsigned short*)&aq[mi][0];
#pragma unroll
        for (int j = 0; j < 16; ++j) { float v = b2f(ap[j]); s = fmaf(v, v, s); }
        s += __shfl_xor(s, 16); s += __shfl_xor(s, 32);
        if (kb == 0) diag_s[mi * 16 + m0] = 0.5f * DN * DN * s;
      }
    }
    f32x4 da[2] = {};
#pragma unroll
    for (int ks = 0; ks < 2; ++ks)
#pragma unroll
      for (int mi = 0; mi < 2; ++mi)
        da[mi] = __builtin_amdgcn_mfma_f32_16x16x32_bf16(aq[mi][ks], bp[ks], da[mi], 0, 0, 0);
#pragma unroll
    for (int mi = 0; mi < 2; ++mi)
#pragma unroll
      for (int r = 0; r < 4; ++r)
        ddl[(mi * 16 + kb * 4 + r) * 74 + w * 16 + m0] = da[mi][r] * DN;
    __syncthreads();
    // ---- exp phase: thread (fl, q): feature fl, tokens q*8..+7 ----
    {
      unsigned int pk[4];
#pragma unroll
      for (int j = 0; j < 8; ++j) {
        int nl = q * 8 + j;
        float kp = 0.f;
        if (nl < tlim)
          kp = RM * (__expf(ddl[nl * 74 + fl] - diag_s[nl] - kmax) + EPSK);
        ksum += kp;
        unsigned int h = (unsigned int)f2b(kp);
        if (j & 1) pk[j >> 1] |= h << 16; else pk[j >> 1] = h;
      }
      *(uint2*)&kpT[fl * 44 + q * 8]     = make_uint2(pk[0], pk[1]);
      *(uint2*)&kpT[fl * 44 + q * 8 + 4] = make_uint2(pk[2], pk[3]);
    }
    __syncthreads();
    // ---- ctx MFMA: A = kpT rows (wave's 16 features), B = VT rows (d), K = 32 ----
    bf16x8 af = ld8s(&kpT[(w * 16 + m0) * 44 + kb * 8]);
#pragma unroll
    for (int di = 0; di < 4; ++di) {
      bf16x8 bfv = ld8s(&VT[(di * 16 + m0) * 44 + kb * 8]);
      acc[di] = __builtin_amdgcn_mfma_f32_16x16x32_bf16(af, bfv, acc[di], 0, 0, 0);
    }
  }
  // ---- epilogue ----
  ksum_lds[tid] = ksum;
  __syncthreads();
  if (tid < 64)
    kpsum[(size_t)bh * MM + mg * 64 + tid] =
        ksum_lds[tid] + ksum_lds[64 + tid] + ksum_lds[128 + tid] + ksum_lds[192 + tid];
  unsigned short* cT = ctxTb + (size_t)bh * (64 * 256);
#pragma unroll
  for (int di = 0; di < 4; ++di)
#pragma unroll
    for (int r = 0; r < 4; ++r) {
      int m = mg * 64 + w * 16 + kb * 4 + r;
      int d = di * 16 + m0;
      cT[d * 256 + m] = f2b(acc[di][r]);
    }
}

// ====== FAVOR query pass (MFMA, XCD-swizzled, conflict-reduced ddl) ======
__global__ __launch_bounds__(256) void qfeat_k(const unsigned short* __restrict__ qq,
    const unsigned short* __restrict__ projb,
    const unsigned short* __restrict__ ctxTb,
    const float* __restrict__ kpsum, unsigned short* __restrict__ o) {
  int orig = blockIdx.y * gridDim.x + blockIdx.x;   // grid (256,13) = 3328
  int wg = ((orig & 7) * 416) + (orig >> 3);
  int bh = wg / 13, gy = wg % 13;
  int b = bh >> 3, hh = bh & 7;
  int tid = threadIdx.x;
  int lane = tid & 63, w = tid >> 6;
  int m0 = lane & 15, kb = lane >> 4;
  __shared__ float ddl[32 * 266];          // stride 266: kb-banks distinct
  __shared__ unsigned short Pb[32 * 264];
  __shared__ float ksum_s[256];
  __shared__ float diag_s[32];
  __shared__ float dinv_s[32];
  ksum_s[tid] = kpsum[(size_t)bh * MM + tid];
  bf16x8 bp[4][2], bc[8];
#pragma unroll
  for (int nf = 0; nf < 4; ++nf)
#pragma unroll
    for (int ks = 0; ks < 2; ++ks)
      bp[nf][ks] = *(const bf16x8*)(projb + (size_t)(w * 64 + nf * 16 + m0) * 64 + ks * 32 + kb * 8);
  const unsigned short* cT = ctxTb + (size_t)bh * (64 * 256);
#pragma unroll
  for (int ks = 0; ks < 8; ++ks)
    bc[ks] = *(const bf16x8*)(cT + (size_t)(w * 16 + m0) * 256 + ks * 32 + kb * 8);
  int t8 = tid >> 3, q8 = tid & 7;
  for (int t = gy; t < 65; t += 13) {
    int n0 = t * 32;
    int tlim = NTOK - n0; if (tlim > 32) tlim = 32;
    bf16x8 aq[2][2];
#pragma unroll
    for (int mi = 0; mi < 2; ++mi) {
      int n = n0 + mi * 16 + m0; if (n >= NTOK) n = NTOK - 1;
#pragma unroll
      for (int ks = 0; ks < 2; ++ks)
        aq[mi][ks] = *(const bf16x8*)(qq + ((size_t)b * NTOK + n) * DD + hh * DHD + ks * 32 + kb * 8);
    }
#pragma unroll
    for (int mi = 0; mi < 2; ++mi) {
      float s = 0.f;
      const unsigned short* ap = (const unsigned short*)&aq[mi][0];
#pragma unroll
      for (int j = 0; j < 16; ++j) { float v = b2f(ap[j]); s = fmaf(v, v, s); }
      s += __shfl_xor(s, 16); s += __shfl_xor(s, 32);
      if (w == 0 && kb == 0) diag_s[mi * 16 + m0] = 0.5f * DN * DN * s;
    }
    f32x4 da[2][4] = {};
#pragma unroll
    for (int ks = 0; ks < 2; ++ks)
#pragma unroll
      for (int mi = 0; mi < 2; ++mi)
#pragma unroll
        for (int nf = 0; nf < 4; ++nf)
          da[mi][nf] = __builtin_amdgcn_mfma_f32_16x16x32_bf16(aq[mi][ks], bp[nf][ks], da[mi][nf], 0, 0, 0);
#pragma unroll
    for (int mi = 0; mi < 2; ++mi)
#pragma unroll
      for (int nf = 0; nf < 4; ++nf)
#pragma unroll
        for (int r = 0; r < 4; ++r)
          ddl[(mi * 16 + kb * 4 + r) * 266 + w * 64 + nf * 16 + m0] = da[mi][nf][r] * DN;
    __syncthreads();
    float mx = -1e30f;
    if (t8 < tlim) {
      for (int j = 0; j < 32; ++j) mx = fmaxf(mx, ddl[t8 * 266 + q8 + 8 * j]);
    }
    mx = fmaxf(mx, __shfl_xor(mx, 1));
    mx = fmaxf(mx, __shfl_xor(mx, 2));
    mx = fmaxf(mx, __shfl_xor(mx, 4));
    float den = 0.f;
    if (t8 < tlim) {
      float dg = diag_s[t8];
      for (int j = 0; j < 32; ++j) {
        int mm = q8 + 8 * j;
        float e = RM * (__expf(ddl[t8 * 266 + mm] - dg - mx) + EPSK);
        Pb[t8 * 264 + mm] = f2b(e);
        den = fmaf(e, ksum_s[mm], den);
      }
    }
    den += __shfl_xor(den, 1); den += __shfl_xor(den, 2); den += __shfl_xor(den, 4);
    if (q8 == 0 && t8 < tlim) dinv_s[t8] = 1.0f / den;
    __syncthreads();
    f32x4 oa[2] = {};
#pragma unroll
    for (int ks = 0; ks < 8; ++ks)
#pragma unroll
      for (int mi = 0; mi < 2; ++mi) {
        bf16x8 ap = *(const bf16x8*)&Pb[(mi * 16 + m0) * 264 + ks * 32 + kb * 8];
        oa[mi] = __builtin_amdgcn_mfma_f32_16x16x32_bf16(ap, bc[ks], oa[mi], 0, 0, 0);
      }
#pragma unroll
    for (int mi = 0; mi < 2; ++mi)
#pragma unroll
      for (int r = 0; r < 4; ++r) {
        int row = mi * 16 + kb * 4 + r;
        if (row < tlim) {
          o[((size_t)b * NTOK + n0 + row) * DD + hh * DHD + w * 16 + m0] =
              f2b(oa[mi][r] * dinv_s[row]);
        }
      }
    __syncthreads();
  }
}

// ======= final cross-attention, 4-phase parallel =======
__global__ __launch_bounds__(256) void attn_sc_k(const unsigned short* __restrict__ qc,
    const unsigned short* __restrict__ kc, float* __restrict__ scbuf,
    float* __restrict__ pmax) {
  int b = blockIdx.x, g = blockIdx.y, tid = threadIdx.x;
  int w = tid >> 6, lane = tid & 63;
  __shared__ float qs[DD];
  __shared__ float red[4];
  {
    ushort2 qu = ((const ushort2*)(qc + (size_t)b * DD))[tid];
    ((float2*)qs)[tid] = make_float2(b2f(qu.x), b2f(qu.y));
  }
  __syncthreads();
  float mx = -1e30f;
  for (int it = 0; it < 64; ++it) {
    int kk = g * 256 + w * 64 + it;
    const unsigned short* row = kc + ((size_t)b * NTOK + 1 + kk) * DD + lane * 8;
    float4 r0 = ld4(row), r1 = ld4(row + 4);
    float4 q0 = ((const float4*)qs)[lane * 2], q1 = ((const float4*)qs)[lane * 2 + 1];
    float s = r0.x * q0.x + r0.y * q0.y + r0.z * q0.z + r0.w * q0.w
            + r1.x * q1.x + r1.y * q1.y + r1.z * q1.z + r1.w * q1.w;
    s = wsum(s) * 0.044194173824159216f; // 1/sqrt(512)
    if (lane == 0) scbuf[(size_t)b * KK + kk] = s;
    mx = fmaxf(mx, s);
  }
  if (lane == 0) red[w] = mx;
  __syncthreads();
  if (tid == 0) pmax[b * 8 + g] = fmaxf(fmaxf(red[0], red[1]), fmaxf(red[2], red[3]));
}
__global__ __launch_bounds__(256) void attn_w_k(const float* __restrict__ pmax,
    float* __restrict__ scbuf, float* __restrict__ pinv) {
  int b = blockIdx.x, tid = threadIdx.x;
  __shared__ float red[4];
  float mx = -1e30f;
#pragma unroll
  for (int i = 0; i < 8; ++i) mx = fmaxf(mx, pmax[b * 8 + i]);
  float sum = 0.f;
  for (int i = tid; i < KK; i += 256) {
    float e = __expf(scbuf[(size_t)b * KK + i] - mx);
    scbuf[(size_t)b * KK + i] = e;
    sum += e;
  }
  sum = wsum(sum);
  if ((tid & 63) == 0) red[tid >> 6] = sum;
  __syncthreads();
  if (tid == 0) pinv[b] = 1.0f / (red[0] + red[1] + red[2] + red[3]);
}
__global__ __launch_bounds__(256) void attn_vs_k(const float* __restrict__ scbuf,
    const unsigned short* __restrict__ vc, float* __restrict__ ppart) {
  int b = blockIdx.x, g = blockIdx.y, tid = threadIdx.x;
  float2 acc = {0.f, 0.f};
  for (int it = 0; it < 256; ++it) {
    int kk = g * 256 + it;
    float wgt = scbuf[(size_t)b * KK + kk];
    ushort2 vu = ((const ushort2*)(vc + ((size_t)b * NTOK + 1 + kk) * DD))[tid];
    acc.x = fmaf(wgt, b2f(vu.x), acc.x);
    acc.y = fmaf(wgt, b2f(vu.y), acc.y);
  }
  ((float2*)(ppart + ((size_t)b * 8 + g) * DD))[tid] = acc;
}
__global__ __launch_bounds__(256) void attn_red_k(const float* __restrict__ ppart,
    const float* __restrict__ pinv, float* __restrict__ pooled) {
  int b = blockIdx.x, tid = threadIdx.x;
  float inv = pinv[b];
  float2 acc = {0.f, 0.f};
#pragma unroll
  for (int g = 0; g < 8; ++g) {
    float2 p = ((const float2*)(ppart + ((size_t)b * 8 + g) * DD))[tid];
    acc.x += p.x; acc.y += p.y;
  }
  ((float2*)(pooled + (size_t)b * DD))[tid] = make_float2(acc.x * inv, acc.y * inv);
}

// ---------------- final projection, fp32 out ----------------
__global__ __launch_bounds__(256) void out_k(const float* __restrict__ pooled,
    const float* __restrict__ co_w, const float* __restrict__ co_b,
    float* __restrict__ out) {
  int b = blockIdx.x, tid = threadIdx.x;
  __shared__ float ps[DD];
  ((float2*)ps)[tid] = ((const float2*)(pooled + (size_t)b * DD))[tid];
  __syncthreads();
  float a0 = co_b[tid], a1 = co_b[tid + 256];
  for (int d = 0; d < 512; ++d) {
    float p = ps[d];
    a0 = fmaf(p, co_w[(size_t)d * 512 + tid], a0);
    a1 = fmaf(p, co_w[(size_t)d * 512 + tid + 256], a1);
  }
  out[(size_t)b * 512 + tid] = a0;
  out[(size_t)b * 512 + tid + 256] = a1;
}

extern "C" void kernel_launch(void* const* d_in, const int* in_sizes, int n_in,
                              void* d_out, int out_size, void* d_ws, size_t ws_size,
                              hipStream_t stream) {
  const float* expr       = (const float*)d_in[0];
  const float* coords     = (const float*)d_in[1];
  const int*   gene_ids   = (const int*)d_in[2];
  const float* gene_table = (const float*)d_in[3];
  const float* pos_table  = (const float*)d_in[4];
  const float* value_tab  = (const float*)d_in[5];
  const float* sp_w  = (const float*)d_in[6];
  const float* sp_b  = (const float*)d_in[7];
  const float* sp_g  = (const float*)d_in[8];
  const float* sp_bb = (const float*)d_in[9];
  const float* ln1_g = (const float*)d_in[10];
  const float* ln1_b = (const float*)d_in[11];
  const float* qw = (const float*)d_in[12];
  const float* qbias = (const float*)d_in[13];
  const float* kw = (const float*)d_in[14];
  const float* kbias = (const float*)d_in[15];
  const float* vw = (const float*)d_in[16];
  const float* vbias = (const float*)d_in[17];
  const float* ow = (const float*)d_in[18];
  const float* obias = (const float*)d_in[19];
  const float* proj  = (const float*)d_in[20];
  const float* ln2_g = (const float*)d_in[21];
  const float* ln2_b = (const float*)d_in[22];
  const float* ff1w = (const float*)d_in[23];
  const float* ff1b = (const float*)d_in[24];
  const float* ff2w = (const float*)d_in[25];
  const float* ff2b = (const float*)d_in[26];
  const float* cqw = (const float*)d_in[27];
  const float* cqb = (const float*)d_in[28];
  const float* ckw = (const float*)d_in[29];
  const float* ckb = (const float*)d_in[30];
  const float* cvw = (const float*)d_in[31];
  const float* cvb = (const float*)d_in[32];
  const float* cow = (const float*)d_in[33];
  const float* cob = (const float*)d_in[34];
  float* out = (float*)d_out;

  const size_t SZ = (size_t)RTOT * DD;
  const size_t MS = (size_t)DD * DD;
  const size_t FS = (size_t)DD * 4 * DD;
  const size_t LST = 4 * MS + 2 * FS;
  const size_t WBN = 4 * LST + 2 * MS;
  const size_t CTXN = (size_t)BB * NH * 64 * 256;

  float* x = (float*)d_ws;
  unsigned short* Ab = (unsigned short*)(x + SZ);
  unsigned short* Bb = Ab + SZ;
  unsigned short* Cb = Bb + SZ;
  unsigned short* wb = Cb + SZ;
  unsigned short* ctxTb = wb + WBN;
  unsigned short* projb = ctxTb + CTXN;
  float* kpsum = (float*)(projb + (size_t)NL * MM * DHD);
  float* pooled = kpsum + (size_t)BB * NH * MM;
  float* bmax  = pooled + (size_t)BB * DD;
  float* kmaxg = bmax + 2816;
  float* scbuf = kmaxg + 16;
  float* pmax  = scbuf + (size_t)BB * KK;
  float* pinv  = pmax + 256;
  float* ppart = pinv + 32;
  unsigned short* qcb = (unsigned short*)(ppart + (size_t)BB * 8 * DD);
  size_t need = (size_t)((char*)(qcb + (size_t)BB * DD) - (char*)d_ws) + 256;
  if (ws_size < need) {
    sentinel_k<<<(out_size + 255) / 256, 256, 0, stream>>>(out, out_size);
    return;
  }

  for (int l = 0; l < NL; ++l) {
    unsigned short* wl = wb + l * LST;
    wcvt_k<<<dim3(8, 8), 256, 0, stream>>>(kw + l * MS, wl,          512, 512);
    wcvt_k<<<dim3(8, 8), 256, 0, stream>>>(vw + l * MS, wl + MS,     512, 512);
    wcvt_k<<<dim3(8, 8), 256, 0, stream>>>(qw + l * MS, wl + 2 * MS, 512, 512);
    wcvt_k<<<dim3(8, 8), 256, 0, stream>>>(ow + l * MS, wl + 3 * MS, 512, 512);
    wcvt_k<<<dim3(32, 8), 256, 0, stream>>>(ff1w + l * FS, wl + 4 * MS,      512, 2048);
    wcvt_k<<<dim3(8, 32), 256, 0, stream>>>(ff2w + l * FS, wl + 4 * MS + FS, 2048, 512);
  }
  wcvt_k<<<dim3(8, 8), 256, 0, stream>>>(ckw, wb + 4 * LST,      512, 512);
  wcvt_k<<<dim3(8, 8), 256, 0, stream>>>(cvw, wb + 4 * LST + MS, 512, 512);
  cvt_k<<<32, 256, 0, stream>>>(proj, projb, (size_t)NL * MM * DHD / 8);

  embed_k<<<BB * KK / 2, 256, 0, stream>>>(expr, gene_ids, gene_table, pos_table, value_tab, x);
  sp_k<<<BB, 256, 0, stream>>>(coords, sp_w, sp_b, sp_g, sp_bb, x);

  const int RB = (RTOT + 127) / 128;   // 513
  const int QB = (QROWS + 127) / 128;  // 129
  for (int l = 0; l < NL; ++l) {
    unsigned short* wl = wb + l * LST;
    const unsigned short* pbl = projb + (size_t)l * MM * DHD;
    ln_k<<<RTOT, 128, 0, stream>>>(x, ln1_g + l * DD, ln1_b + l * DD, Cb);
    gemm_bb<unsigned short, 0><<<dim3(4, RB), 256, 0, stream>>>(Cb, DD,
        wl, kbias + l * DD, Ab, DD, RTOT, DD);
    gemm_bb<unsigned short, 0><<<dim3(4, RB), 256, 0, stream>>>(Cb, DD,
        wl + MS, vbias + l * DD, Bb, DD, RTOT, DD);
    kmax_k<<<dim3(256, 4), 256, 0, stream>>>(Ab, pbl, bmax);
    maxred_k<<<1, 256, 0, stream>>>(bmax, BB * NH * 4, kmaxg);
    k2_k<<<dim3(256, 4), 256, 0, stream>>>(Ab, Bb, pbl, kmaxg, ctxTb, kpsum);
    gemm_bb<unsigned short, 0><<<dim3(4, RB), 256, 0, stream>>>(Cb, DD,
        wl + 2 * MS, qbias + l * DD, Ab, DD, RTOT, DD);
    qfeat_k<<<dim3(256, 13), 256, 0, stream>>>(Ab, pbl, ctxTb, kpsum, Bb);
    gemm_bb<float, 2><<<dim3(4, RB), 256, 0, stream>>>(Bb, DD,
        wl + 3 * MS, obias + l * DD, x, DD, RTOT, DD);
    ln_k<<<RTOT, 128, 0, stream>>>(x, ln2_g + l * DD, ln2_b + l * DD, Cb);
    for (int c = 0; c < 4; ++c) {
      gemm_bb<unsigned short, 1><<<dim3(16, QB), 256, 0, stream>>>(Cb + (size_t)c * QROWS * DD, DD,
          wl + 4 * MS, ff1b + (size_t)l * 4 * DD, Ab, 4 * DD, QROWS, DD);
      gemm_bb<float, 2><<<dim3(4, QB), 256, 0, stream>>>(Ab, 4 * DD,
          wl + 4 * MS + FS, ff2b + l * DD, x + (size_t)c * QROWS * DD, DD, QROWS, 4 * DD);
    }
  }
  cvt_k<<<(int)(SZ / 8 / 256), 256, 0, stream>>>(x, Cb, SZ / 8);
  gemm_bb<unsigned short, 0><<<dim3(4, RB), 256, 0, stream>>>(Cb, DD,
      wb + 4 * LST, ckb, Ab, DD, RTOT, DD);       // kc
  gemm_bb<unsigned short, 0><<<dim3(4, RB), 256, 0, stream>>>(Cb, DD,
      wb + 4 * LST + MS, cvb, Bb, DD, RTOT, DD);  // vc
  gemm_t<float, unsigned short><<<dim3(8, 1), 256, 0, stream>>>(x, (long)NTOK * DD,
      cqw, cqb, qcb, DD, BB, DD, DD);             // qc (token 0 per batch)
  attn_sc_k<<<dim3(BB, 8), 256, 0, stream>>>(qcb, Ab, scbuf, pmax);
  attn_w_k<<<BB, 256, 0, stream>>>(pmax, scbuf, pinv);
  attn_vs_k<<<dim3(BB, 8), 256, 0, stream>>>(scbuf, Bb, ppart);
  attn_red_k<<<BB, 256, 0, stream>>>(ppart, pinv, pooled);
  out_k<<<BB, 256, 0, stream>>>(pooled, cow, cob, out);
}

// Round 13
// 5999.350 us; speedup vs baseline: 1.0711x; 1.0711x over previous
//
#include <hip/hip_runtime.h>
#include <hip/hip_bf16.h>

#define BB 32
#define KK 2048
#define NTOK 2049
#define DD 512
#define NH 8
#define DHD 64
#define NL 4
#define MM 256
#define RTOT (BB*NTOK)          // 65568
#define HROWS (RTOT/2)          // 32784
#define DN 0.35355339059327373f // 64^-0.25
#define RM 0.0625f              // 256^-0.5
#define EPSK 1e-4f

typedef __attribute__((ext_vector_type(8))) short bf16x8;
typedef __attribute__((ext_vector_type(4))) float f32x4;

__device__ __forceinline__ float wsum(float v) {
#pragma unroll
  for (int o = 32; o; o >>= 1) v += __shfl_xor(v, o);
  return v;
}
__device__ __forceinline__ float wmax(float v) {
#pragma unroll
  for (int o = 32; o; o >>= 1) v = fmaxf(v, __shfl_xor(v, o));
  return v;
}
__device__ __forceinline__ float gelu1(float v) {
  return 0.5f * v * (1.0f + erff(v * 0.70710678118654752f));
}
__device__ __forceinline__ float b2f(unsigned short u) {
  union { unsigned int i; float f; } w; w.i = ((unsigned int)u) << 16; return w.f;
}
__device__ __forceinline__ unsigned short f2b(float f) {
  union { float f; unsigned int i; } w; w.f = f;
  unsigned int r = w.i + 0x7FFFu + ((w.i >> 16) & 1u);
  return (unsigned short)(r >> 16);
}
__device__ __forceinline__ float4 ld4(const float* p) { return *(const float4*)p; }
__device__ __forceinline__ float4 ld4(const unsigned short* p) {
  ushort4 u = *(const ushort4*)p;
  return make_float4(b2f(u.x), b2f(u.y), b2f(u.z), b2f(u.w));
}
__device__ __forceinline__ void st4(float* p, float4 v) { *(float4*)p = v; }
__device__ __forceinline__ void st4(unsigned short* p, float4 v) {
  ushort4 u; u.x = f2b(v.x); u.y = f2b(v.y); u.z = f2b(v.z); u.w = f2b(v.w);
  *(ushort4*)p = u;
}
__device__ __forceinline__ bf16x8 ld8s(const unsigned short* p) {
  union { ushort4 u[2]; bf16x8 v; } w;
  w.u[0] = *(const ushort4*)p;
  w.u[1] = *(const ushort4*)(p + 4);
  return w.v;
}
__device__ __forceinline__ void gload16(const void* g, void* l) {
  __builtin_amdgcn_global_load_lds(
      (const __attribute__((address_space(1))) void*)g,
      (__attribute__((address_space(3))) void*)l, 16, 0, 0);
}

// ---------------- sentinel: ws too small -> absmax ~1.2e4 ----------------
__global__ void sentinel_k(float* out, int n) {
  int i = blockIdx.x * 256 + threadIdx.x;
  if (i < n) out[i] = 12345.0f;
}

// ---------------- bias pack: dst[0..511]=a, dst[512..1023]=b ----------------
__global__ void biaspack_k(const float* __restrict__ a, const float* __restrict__ bsrc,
                           float* __restrict__ dst) {
  int i = threadIdx.x;
  dst[i] = a[i]; dst[i + 256] = a[i + 256];
  dst[512 + i] = bsrc[i]; dst[768 + i] = bsrc[i + 256];
}

// ---------------- weight convert + transpose: Wt[n][k] = bf16(W[k][n]) ----------------
__global__ __launch_bounds__(256) void wcvt_k(const float* __restrict__ W,
    unsigned short* __restrict__ Wt, int Kd, int Cols) {
  __shared__ float Ls[64][65];
  int tid = threadIdx.x;
  int n0 = blockIdx.x * 64, k0 = blockIdx.y * 64;
  int kr = tid >> 2, nseg = (tid & 3) << 4;
#pragma unroll
  for (int u = 0; u < 4; ++u) {
    float4 v = *(const float4*)(W + (size_t)(k0 + kr) * Cols + n0 + nseg + u * 4);
    *(float4*)&Ls[kr][nseg + u * 4] = v;
  }
  __syncthreads();
  int nr = tid >> 2, kseg = (tid & 3) << 4;
  unsigned int pk[8];
#pragma unroll
  for (int i = 0; i < 8; ++i) {
    unsigned short lo = f2b(Ls[kseg + 2 * i][nr]);
    unsigned short hi = f2b(Ls[kseg + 2 * i + 1][nr]);
    pk[i] = (unsigned int)lo | ((unsigned int)hi << 16);
  }
  unsigned short* dst = Wt + (size_t)(n0 + nr) * Kd + k0 + kseg;
  ((uint4*)dst)[0] = make_uint4(pk[0], pk[1], pk[2], pk[3]);
  ((uint4*)dst)[1] = make_uint4(pk[4], pk[5], pk[6], pk[7]);
}

// ---------------- embedding ----------------
__global__ __launch_bounds__(256) void embed_k(const float* __restrict__ expr,
    const int* __restrict__ gene_ids, const float* __restrict__ gene_table,
    const float* __restrict__ pos_table, const float* __restrict__ value_tab,
    float* __restrict__ x) {
  int tok = blockIdx.x * 2 + (threadIdx.x >> 7);
  int t = threadIdx.x & 127;
  int b = tok >> 11;
  int k = tok & 2047;
  float e = expr[tok];
  int bin = (int)(e * 5.0f);
  bin = bin < 0 ? 0 : (bin > 4 ? 4 : bin);
  int g = gene_ids[k];
  float4 a = ((const float4*)(gene_table + (size_t)g * DD))[t];
  float4 p = ((const float4*)(pos_table + (size_t)k * DD))[t];
  float4 vv = ((const float4*)(value_tab + (size_t)bin * DD))[t];
  float4 r;
  r.x = a.x + p.x + vv.x; r.y = a.y + p.y + vv.y;
  r.z = a.z + p.z + vv.z; r.w = a.w + p.w + vv.w;
  ((float4*)(x + ((size_t)b * NTOK + 1 + k) * DD))[t] = r;
}

// ---------------- spatial token ----------------
__global__ __launch_bounds__(256) void sp_k(const float* __restrict__ coords,
    const float* __restrict__ sp_w, const float* __restrict__ sp_b,
    const float* __restrict__ g, const float* __restrict__ bb,
    float* __restrict__ x) {
  int b = blockIdx.x, t = threadIdx.x;
  __shared__ float red[8];
  float c0 = coords[2 * b], c1 = coords[2 * b + 1];
  float v0 = fmaf(c0, sp_w[t],       fmaf(c1, sp_w[512 + t], sp_b[t]));
  float v1 = fmaf(c0, sp_w[t + 256], fmaf(c1, sp_w[768 + t], sp_b[t + 256]));
  float s = wsum(v0 + v1);
  int wid = t >> 6;
  if ((t & 63) == 0) red[wid] = s;
  __syncthreads();
  float mu = (red[0] + red[1] + red[2] + red[3]) * (1.0f / 512.0f);
  float d0 = v0 - mu, d1 = v1 - mu;
  float s2 = wsum(d0 * d0 + d1 * d1);
  if ((t & 63) == 0) red[4 + wid] = s2;
  __syncthreads();
  float var = (red[4] + red[5] + red[6] + red[7]) * (1.0f / 512.0f);
  float rs = rsqrtf(var + 1e-5f);
  float y0 = d0 * rs * g[t] + bb[t];
  float y1 = d1 * rs * g[t + 256] + bb[t + 256];
  x[(size_t)b * NTOK * DD + t] = gelu1(y0);
  x[(size_t)b * NTOK * DD + t + 256] = gelu1(y1);
}

// ---------------- fused LN -> bf16 ----------------
__global__ __launch_bounds__(128) void ln_k(const float* __restrict__ x,
    const float* __restrict__ gamma, const float* __restrict__ beta,
    unsigned short* __restrict__ h) {
  size_t row = blockIdx.x;
  int t = threadIdx.x;
  float4 v = ((const float4*)(x + row * DD))[t];
  float s = v.x + v.y + v.z + v.w;
  float s2 = v.x * v.x + v.y * v.y + v.z * v.z + v.w * v.w;
  __shared__ float red[4];
  float ws1 = wsum(s), ws2 = wsum(s2);
  int wid = t >> 6;
  if ((t & 63) == 0) { red[wid * 2] = ws1; red[wid * 2 + 1] = ws2; }
  __syncthreads();
  float S = red[0] + red[2], S2 = red[1] + red[3];
  float mu = S * (1.0f / 512.0f);
  float var = S2 * (1.0f / 512.0f) - mu * mu;
  float rs = rsqrtf(var + 1e-5f);
  float4 gm = ((const float4*)gamma)[t], bt = ((const float4*)beta)[t];
  float4 o;
  o.x = (v.x - mu) * rs * gm.x + bt.x;
  o.y = (v.y - mu) * rs * gm.y + bt.y;
  o.z = (v.z - mu) * rs * gm.z + bt.z;
  o.w = (v.w - mu) * rs * gm.w + bt.w;
  st4(h + row * DD + t * 4, o);
}

// ---------------- fp32 -> bf16 convert ----------------
__global__ __launch_bounds__(256) void cvt_k(const float* __restrict__ x,
    unsigned short* __restrict__ o, size_t n8) {
  size_t i = (size_t)blockIdx.x * 256 + threadIdx.x;
  if (i >= n8) return;
  float4 a = ((const float4*)x)[2 * i];
  float4 b = ((const float4*)x)[2 * i + 1];
  st4(o + i * 8, a);
  st4(o + i * 8 + 4, b);
}

// ======= all-bf16 MFMA GEMM, BK=64 + XOR-swizzled LDS + bijective XCD swizzle =======
template <typename TC, int FLAGS>
__global__ __launch_bounds__(256) void gemm_bb(const unsigned short* __restrict__ A, long lda,
    const unsigned short* __restrict__ Wt, const float* __restrict__ bias,
    TC* __restrict__ C, int ldc, int R, int Kd) {
  __shared__ unsigned short As[128 * 64];
  __shared__ unsigned short Bs[128 * 64];
  const int tid = threadIdx.x;
  const int lane = tid & 63;
  const int w = tid >> 6;
  const int wr = w >> 1, wc = w & 1;
  const int nwg = gridDim.x * gridDim.y;
  const int orig = blockIdx.y * gridDim.x + blockIdx.x;
  const int qd = nwg >> 3, rm = nwg & 7;
  const int xcd = orig & 7, idx = orig >> 3;
  const int wg = (xcd < rm ? xcd * (qd + 1) : rm * (qd + 1) + (xcd - rm) * qd) + idx;
  const int rblk = (wg / gridDim.x) << 7;
  const int cblk = (wg % gridDim.x) << 7;
  const int m0 = lane & 15, kb = lane >> 4;
  const int lrow8 = lane >> 3;
  const int csw = (((lane & 7) ^ lrow8) << 3);
  f32x4 acc[4][4] = {};
  for (int k0 = 0; k0 < Kd; k0 += 64) {
#pragma unroll
    for (int rd = 0; rd < 4; ++rd) {
      int rg = w * 32 + rd * 8;
      int gra = rblk + rg + lrow8; if (gra >= R) gra = R - 1;
      gload16(A  + (size_t)gra * lda + k0 + csw, &As[rg * 64]);
      gload16(Wt + (size_t)(cblk + rg + lrow8) * Kd + k0 + csw, &Bs[rg * 64]);
    }
    __syncthreads();
    bf16x8 af[2][4], bfr[2][4];
#pragma unroll
    for (int ks = 0; ks < 2; ++ks) {
      int c = (ks << 2) | kb;
#pragma unroll
      for (int mi = 0; mi < 4; ++mi) {
        int ar = wr * 64 + mi * 16 + m0;
        af[ks][mi] = *(const bf16x8*)&As[ar * 64 + ((c ^ (ar & 7)) << 3)];
        int br = wc * 64 + mi * 16 + m0;
        bfr[ks][mi] = *(const bf16x8*)&Bs[br * 64 + ((c ^ (br & 7)) << 3)];
      }
    }
#pragma unroll
    for (int ks = 0; ks < 2; ++ks)
#pragma unroll
      for (int mi = 0; mi < 4; ++mi)
#pragma unroll
        for (int ni = 0; ni < 4; ++ni)
          acc[mi][ni] = __builtin_amdgcn_mfma_f32_16x16x32_bf16(af[ks][mi], bfr[ks][ni], acc[mi][ni], 0, 0, 0);
    __syncthreads();
  }
  const int lrow4 = (lane >> 4) << 2, lcol = lane & 15;
#pragma unroll
  for (int mi = 0; mi < 4; ++mi) {
#pragma unroll
    for (int reg = 0; reg < 4; ++reg) {
      int row = rblk + wr * 64 + mi * 16 + lrow4 + reg;
      if (row < R) {
#pragma unroll
        for (int ni = 0; ni < 4; ++ni) {
          int col = cblk + wc * 64 + ni * 16 + lcol;
          float v = acc[mi][ni][reg] + bias[col];
          if constexpr ((FLAGS & 1) != 0) v = gelu1(v);
          if constexpr (sizeof(TC) == 4) {
            float* cp = (float*)C + (size_t)row * ldc + col;
            if constexpr ((FLAGS & 2) != 0) v += *cp;
            *cp = v;
          } else {
            unsigned short* cp = (unsigned short*)C + (size_t)row * ldc + col;
            if constexpr ((FLAGS & 2) != 0) v += b2f(*cp);
            *cp = f2b(v);
          }
        }
      }
    }
  }
}

// ---------------- fp32 tile GEMM (tiny qc only) ----------------
template <typename TA, typename TC>
__global__ __launch_bounds__(256) void gemm_t(const TA* __restrict__ A, long lda,
    const float* __restrict__ W, const float* __restrict__ bias,
    TC* __restrict__ C, int ldc, int R, int Kd, int Cols) {
  __shared__ float As[16][68];
  __shared__ float Ws[16][64];
  int tid = threadIdx.x;
  int tx = tid & 15, ty = tid >> 4;
  int rblk = blockIdx.y << 6, cblk = blockIdx.x << 6;
  float acc[4][4] = {};
  int lr = tid >> 2, lk = (tid & 3) << 2;
  int wk = tid >> 4, wcc = (tid & 15) << 2;
  int gra = rblk + lr;
  for (int k0 = 0; k0 < Kd; k0 += 16) {
    float4 av = make_float4(0.f, 0.f, 0.f, 0.f);
    if (gra < R) av = ld4(A + (size_t)gra * lda + k0 + lk);
    As[lk][lr] = av.x; As[lk + 1][lr] = av.y; As[lk + 2][lr] = av.z; As[lk + 3][lr] = av.w;
    *(float4*)&Ws[wk][wcc] = *(const float4*)(W + (size_t)(k0 + wk) * Cols + cblk + wcc);
    __syncthreads();
#pragma unroll
    for (int p = 0; p < 16; ++p) {
      float4 a4 = *(const float4*)&As[p][ty << 2];
      float4 b4 = *(const float4*)&Ws[p][tx << 2];
      acc[0][0] = fmaf(a4.x, b4.x, acc[0][0]); acc[0][1] = fmaf(a4.x, b4.y, acc[0][1]);
      acc[0][2] = fmaf(a4.x, b4.z, acc[0][2]); acc[0][3] = fmaf(a4.x, b4.w, acc[0][3]);
      acc[1][0] = fmaf(a4.y, b4.x, acc[1][0]); acc[1][1] = fmaf(a4.y, b4.y, acc[1][1]);
      acc[1][2] = fmaf(a4.y, b4.z, acc[1][2]); acc[1][3] = fmaf(a4.y, b4.w, acc[1][3]);
      acc[2][0] = fmaf(a4.z, b4.x, acc[2][0]); acc[2][1] = fmaf(a4.z, b4.y, acc[2][1]);
      acc[2][2] = fmaf(a4.z, b4.z, acc[2][2]); acc[2][3] = fmaf(a4.z, b4.w, acc[2][3]);
      acc[3][0] = fmaf(a4.w, b4.x, acc[3][0]); acc[3][1] = fmaf(a4.w, b4.y, acc[3][1]);
      acc[3][2] = fmaf(a4.w, b4.z, acc[3][2]); acc[3][3] = fmaf(a4.w, b4.w, acc[3][3]);
    }
    __syncthreads();
  }
  int gcb = cblk + (tx << 2);
  float4 bi = *(const float4*)(bias + gcb);
#pragma unroll
  for (int i = 0; i < 4; ++i) {
    int gr = rblk + (ty << 2) + i;
    if (gr < R) {
      float4 val;
      val.x = acc[i][0] + bi.x; val.y = acc[i][1] + bi.y;
      val.z = acc[i][2] + bi.z; val.w = acc[i][3] + bi.w;
      TC* cp = C + (size_t)gr * ldc + gcb;
      st4(cp, val);
    }
  }
}

// ------- FAVOR key pass 1 (MFMA, packed KV input): max over dd = K@proj^T -------
__global__ __launch_bounds__(256) void kmax_k(const unsigned short* __restrict__ kv,
    const unsigned short* __restrict__ projb, float* __restrict__ bmax) {
  int orig = blockIdx.y * gridDim.x + blockIdx.x;   // grid (256,4) = 1024
  int wg = ((orig & 7) << 7) + (orig >> 3);
  int bh = wg >> 2, gy = wg & 3;
  int b = bh >> 3, hh = bh & 7;
  int tid = threadIdx.x;
  int lane = tid & 63, w = tid >> 6;
  int m0 = lane & 15, kb = lane >> 4;
  __shared__ float red[4];
  bf16x8 bp[4][2];
#pragma unroll
  for (int nf = 0; nf < 4; ++nf)
#pragma unroll
    for (int ks = 0; ks < 2; ++ks)
      bp[nf][ks] = *(const bf16x8*)(projb + (size_t)(w * 64 + nf * 16 + m0) * 64 + ks * 32 + kb * 8);
  const unsigned short* kvb = kv + (size_t)b * NTOK * 1024 + hh * 64;
  float mx = -1e30f;
  for (int t = gy; t < 65; t += 4) {
    int n0 = t * 32;
    bf16x8 aq[2][2];
#pragma unroll
    for (int mi = 0; mi < 2; ++mi) {
      int n = n0 + mi * 16 + m0; if (n >= NTOK) n = NTOK - 1;
#pragma unroll
      for (int ks = 0; ks < 2; ++ks)
        aq[mi][ks] = *(const bf16x8*)(kvb + (size_t)n * 1024 + ks * 32 + kb * 8);
    }
    f32x4 da[2][4] = {};
#pragma unroll
    for (int ks = 0; ks < 2; ++ks)
#pragma unroll
      for (int mi = 0; mi < 2; ++mi)
#pragma unroll
        for (int nf = 0; nf < 4; ++nf)
          da[mi][nf] = __builtin_amdgcn_mfma_f32_16x16x32_bf16(aq[mi][ks], bp[nf][ks], da[mi][nf], 0, 0, 0);
#pragma unroll
    for (int mi = 0; mi < 2; ++mi)
#pragma unroll
      for (int nf = 0; nf < 4; ++nf)
#pragma unroll
        for (int r = 0; r < 4; ++r)
          mx = fmaxf(mx, da[mi][nf][r]);
  }
  mx *= DN;
  mx = wmax(mx);
  if ((tid & 63) == 0) red[tid >> 6] = mx;
  __syncthreads();
  if (tid == 0)
    bmax[(size_t)bh * 4 + gy] = fmaxf(fmaxf(red[0], red[1]), fmaxf(red[2], red[3]));
}

__global__ __launch_bounds__(256) void maxred_k(const float* __restrict__ in, int n,
                                                float* __restrict__ out) {
  float m = -1e30f;
  for (int i = threadIdx.x; i < n; i += 256) m = fmaxf(m, in[i]);
  m = wmax(m);
  __shared__ float red[4];
  if ((threadIdx.x & 63) == 0) red[threadIdx.x >> 6] = m;
  __syncthreads();
  if (threadIdx.x == 0) out[0] = fmaxf(fmaxf(red[0], red[1]), fmaxf(red[2], red[3]));
}

// ===== FAVOR key pass 2 v6 (MFMA, in-register exp, packed KV) =====
__global__ __launch_bounds__(256) void k2_k(const unsigned short* __restrict__ kv,
    const unsigned short* __restrict__ projb,
    const float* __restrict__ kmaxg, unsigned short* __restrict__ ctxTb,
    float* __restrict__ kpsum) {
  int orig = blockIdx.y * gridDim.x + blockIdx.x;   // grid (256,4) = 1024
  int wg = ((orig & 7) << 7) + (orig >> 3);
  int bh = wg >> 2, mg = wg & 3;
  int b = bh >> 3, hh = bh & 7;
  int tid = threadIdx.x;
  int lane = tid & 63, w = tid >> 6;
  int m0 = lane & 15, kb = lane >> 4;
  __shared__ __align__(16) unsigned short kpT[64 * 44];
  __shared__ __align__(16) unsigned short VT[64 * 44];
  float kmax = kmaxg[0];
  bf16x8 bp[2];
#pragma unroll
  for (int ks = 0; ks < 2; ++ks)
    bp[ks] = *(const bf16x8*)(projb + (size_t)(mg * 64 + w * 16 + m0) * 64 + ks * 32 + kb * 8);
  f32x4 acc[4] = {};
  float ksum = 0.f;
  int dv = tid & 63, tq = tid >> 6;
  const unsigned short* kvb = kv + (size_t)b * NTOK * 1024 + hh * 64;
  for (int t = 0; t < 65; ++t) {
    int n0 = t * 32;
    int tlim = NTOK - n0; if (tlim > 32) tlim = 32;
    __syncthreads();
    // ---- stage V^T: thread (dv, tq) packs 8 tokens of dim dv ----
    {
      unsigned int pk[4];
#pragma unroll
      for (int j = 0; j < 8; ++j) {
        int n = n0 + tq * 8 + j; if (n >= NTOK) n = NTOK - 1;
        unsigned int v = kvb[(size_t)n * 1024 + 512 + dv];
        if (j & 1) pk[j >> 1] |= v << 16; else pk[j >> 1] = v;
      }
      *(uint2*)&VT[dv * 44 + tq * 8]     = make_uint2(pk[0], pk[1]);
      *(uint2*)&VT[dv * 44 + tq * 8 + 4] = make_uint2(pk[2], pk[3]);
    }
    // ---- load K rows + per-lane partial sumsq (diag via shfl, no LDS) ----
    bf16x8 aq[2][2];
    float dg[2];
#pragma unroll
    for (int mi = 0; mi < 2; ++mi) {
      int n = n0 + mi * 16 + m0; if (n >= NTOK) n = NTOK - 1;
      float s = 0.f;
#pragma unroll
      for (int ks = 0; ks < 2; ++ks) {
        aq[mi][ks] = *(const bf16x8*)(kvb + (size_t)n * 1024 + ks * 32 + kb * 8);
        const unsigned short* ap = (const unsigned short*)&aq[mi][ks];
#pragma unroll
        for (int j = 0; j < 8; ++j) { float v = b2f(ap[j]); s = fmaf(v, v, s); }
      }
      s += __shfl_xor(s, 16);
      s += __shfl_xor(s, 32);
      dg[mi] = 0.5f * DN * DN * s;   // diag for token n0 + mi*16 + m0
    }
    // ---- dd MFMA ----
    f32x4 da[2] = {};
#pragma unroll
    for (int ks = 0; ks < 2; ++ks)
#pragma unroll
      for (int mi = 0; mi < 2; ++mi)
        da[mi] = __builtin_amdgcn_mfma_f32_16x16x32_bf16(aq[mi][ks], bp[ks], da[mi], 0, 0, 0);
    // ---- in-register exp + pack kp (feature w*16+m0, tokens mi*16+kb*4+r) ----
#pragma unroll
    for (int mi = 0; mi < 2; ++mi) {
      unsigned int pk[2];
#pragma unroll
      for (int r = 0; r < 4; ++r) {
        float dval = __shfl(dg[mi], (kb << 2) | r);
        int tt = mi * 16 + (kb << 2) + r;
        float kp = 0.f;
        if (tt < tlim)
          kp = RM * (__expf(da[mi][r] * DN - dval - kmax) + EPSK);
        ksum += kp;
        unsigned int h = (unsigned int)f2b(kp);
        if (r & 1) pk[r >> 1] |= h << 16; else pk[r >> 1] = h;
      }
      *(uint2*)&kpT[(w * 16 + m0) * 44 + mi * 16 + (kb << 2)] = make_uint2(pk[0], pk[1]);
    }
    __syncthreads();
    // ---- ctx MFMA: A = kpT rows (features), B = VT rows (d), K = 32 ----
    bf16x8 af = ld8s(&kpT[(w * 16 + m0) * 44 + kb * 8]);
#pragma unroll
    for (int di = 0; di < 4; ++di) {
      bf16x8 bfv = ld8s(&VT[(di * 16 + m0) * 44 + kb * 8]);
      acc[di] = __builtin_amdgcn_mfma_f32_16x16x32_bf16(af, bfv, acc[di], 0, 0, 0);
    }
  }
  // ---- epilogue: ksum reduce across kb lanes via shfl ----
  ksum += __shfl_xor(ksum, 16);
  ksum += __shfl_xor(ksum, 32);
  if (kb == 0) kpsum[(size_t)bh * MM + mg * 64 + w * 16 + m0] = ksum;
  unsigned short* cT = ctxTb + (size_t)bh * (64 * 256);
#pragma unroll
  for (int di = 0; di < 4; ++di)
#pragma unroll
    for (int r = 0; r < 4; ++r) {
      int m = mg * 64 + w * 16 + (kb << 2) + r;
      int d = di * 16 + m0;
      cT[d * 256 + m] = f2b(acc[di][r]);
    }
}

// ====== FAVOR query pass (MFMA, packed KV: Q in cols 0-511, o -> cols 512-1023) ======
__global__ __launch_bounds__(256) void qfeat_k(unsigned short* __restrict__ kv,
    const unsigned short* __restrict__ projb,
    const unsigned short* __restrict__ ctxTb,
    const float* __restrict__ kpsum) {
  int orig = blockIdx.y * gridDim.x + blockIdx.x;   // grid (256,13) = 3328
  int wg = ((orig & 7) * 416) + (orig >> 3);
  int bh = wg / 13, gy = wg % 13;
  int b = bh >> 3, hh = bh & 7;
  int tid = threadIdx.x;
  int lane = tid & 63, w = tid >> 6;
  int m0 = lane & 15, kb = lane >> 4;
  __shared__ float ddl[32 * 266];
  __shared__ unsigned short Pb[32 * 264];
  __shared__ float ksum_s[256];
  __shared__ float diag_s[32];
  __shared__ float dinv_s[32];
  ksum_s[tid] = kpsum[(size_t)bh * MM + tid];
  bf16x8 bp[4][2], bc[8];
#pragma unroll
  for (int nf = 0; nf < 4; ++nf)
#pragma unroll
    for (int ks = 0; ks < 2; ++ks)
      bp[nf][ks] = *(const bf16x8*)(projb + (size_t)(w * 64 + nf * 16 + m0) * 64 + ks * 32 + kb * 8);
  const unsigned short* cT = ctxTb + (size_t)bh * (64 * 256);
#pragma unroll
  for (int ks = 0; ks < 8; ++ks)
    bc[ks] = *(const bf16x8*)(cT + (size_t)(w * 16 + m0) * 256 + ks * 32 + kb * 8);
  unsigned short* kvb = kv + (size_t)b * NTOK * 1024 + hh * 64;
  int t8 = tid >> 3, q8 = tid & 7;
  for (int t = gy; t < 65; t += 13) {
    int n0 = t * 32;
    int tlim = NTOK - n0; if (tlim > 32) tlim = 32;
    bf16x8 aq[2][2];
#pragma unroll
    for (int mi = 0; mi < 2; ++mi) {
      int n = n0 + mi * 16 + m0; if (n >= NTOK) n = NTOK - 1;
#pragma unroll
      for (int ks = 0; ks < 2; ++ks)
        aq[mi][ks] = *(const bf16x8*)(kvb + (size_t)n * 1024 + ks * 32 + kb * 8);
    }
#pragma unroll
    for (int mi = 0; mi < 2; ++mi) {
      float s = 0.f;
      const unsigned short* ap = (const unsigned short*)&aq[mi][0];
#pragma unroll
      for (int j = 0; j < 16; ++j) { float v = b2f(ap[j]); s = fmaf(v, v, s); }
      s += __shfl_xor(s, 16); s += __shfl_xor(s, 32);
      if (w == 0 && kb == 0) diag_s[mi * 16 + m0] = 0.5f * DN * DN * s;
    }
    f32x4 da[2][4] = {};
#pragma unroll
    for (int ks = 0; ks < 2; ++ks)
#pragma unroll
      for (int mi = 0; mi < 2; ++mi)
#pragma unroll
        for (int nf = 0; nf < 4; ++nf)
          da[mi][nf] = __builtin_amdgcn_mfma_f32_16x16x32_bf16(aq[mi][ks], bp[nf][ks], da[mi][nf], 0, 0, 0);
#pragma unroll
    for (int mi = 0; mi < 2; ++mi)
#pragma unroll
      for (int nf = 0; nf < 4; ++nf)
#pragma unroll
        for (int r = 0; r < 4; ++r)
          ddl[(mi * 16 + kb * 4 + r) * 266 + w * 64 + nf * 16 + m0] = da[mi][nf][r] * DN;
    __syncthreads();
    float mx = -1e30f;
    if (t8 < tlim) {
      for (int j = 0; j < 32; ++j) mx = fmaxf(mx, ddl[t8 * 266 + q8 + 8 * j]);
    }
    mx = fmaxf(mx, __shfl_xor(mx, 1));
    mx = fmaxf(mx, __shfl_xor(mx, 2));
    mx = fmaxf(mx, __shfl_xor(mx, 4));
    float den = 0.f;
    if (t8 < tlim) {
      float dg = diag_s[t8];
      for (int j = 0; j < 32; ++j) {
        int mm = q8 + 8 * j;
        float e = RM * (__expf(ddl[t8 * 266 + mm] - dg - mx) + EPSK);
        Pb[t8 * 264 + mm] = f2b(e);
        den = fmaf(e, ksum_s[mm], den);
      }
    }
    den += __shfl_xor(den, 1); den += __shfl_xor(den, 2); den += __shfl_xor(den, 4);
    if (q8 == 0 && t8 < tlim) dinv_s[t8] = 1.0f / den;
    __syncthreads();
    f32x4 oa[2] = {};
#pragma unroll
    for (int ks = 0; ks < 8; ++ks)
#pragma unroll
      for (int mi = 0; mi < 2; ++mi) {
        bf16x8 ap = *(const bf16x8*)&Pb[(mi * 16 + m0) * 264 + ks * 32 + kb * 8];
        oa[mi] = __builtin_amdgcn_mfma_f32_16x16x32_bf16(ap, bc[ks], oa[mi], 0, 0, 0);
      }
#pragma unroll
    for (int mi = 0; mi < 2; ++mi)
#pragma unroll
      for (int r = 0; r < 4; ++r) {
        int row = mi * 16 + kb * 4 + r;
        if (row < tlim) {
          kvb[(size_t)(n0 + row) * 1024 + 512 + w * 16 + m0] =
              f2b(oa[mi][r] * dinv_s[row]);
        }
      }
    __syncthreads();
  }
}

// ======= final cross-attention, 4-phase parallel (packed kc|vc) =======
__global__ __launch_bounds__(256) void attn_sc_k(const unsigned short* __restrict__ qc,
    const unsigned short* __restrict__ kcvc, float* __restrict__ scbuf,
    float* __restrict__ pmax) {
  int b = blockIdx.x, g = blockIdx.y, tid = threadIdx.x;
  int w = tid >> 6, lane = tid & 63;
  __shared__ float qs[DD];
  __shared__ float red[4];
  {
    ushort2 qu = ((const ushort2*)(qc + (size_t)b * DD))[tid];
    ((float2*)qs)[tid] = make_float2(b2f(qu.x), b2f(qu.y));
  }
  __syncthreads();
  float mx = -1e30f;
  for (int it = 0; it < 64; ++it) {
    int kk = g * 256 + w * 64 + it;
    const unsigned short* row = kcvc + ((size_t)b * NTOK + 1 + kk) * 1024 + lane * 8;
    float4 r0 = ld4(row), r1 = ld4(row + 4);
    float4 q0 = ((const float4*)qs)[lane * 2], q1 = ((const float4*)qs)[lane * 2 + 1];
    float s = r0.x * q0.x + r0.y * q0.y + r0.z * q0.z + r0.w * q0.w
            + r1.x * q1.x + r1.y * q1.y + r1.z * q1.z + r1.w * q1.w;
    s = wsum(s) * 0.044194173824159216f; // 1/sqrt(512)
    if (lane == 0) scbuf[(size_t)b * KK + kk] = s;
    mx = fmaxf(mx, s);
  }
  if (lane == 0) red[w] = mx;
  __syncthreads();
  if (tid == 0) pmax[b * 8 + g] = fmaxf(fmaxf(red[0], red[1]), fmaxf(red[2], red[3]));
}
__global__ __launch_bounds__(256) void attn_w_k(const float* __restrict__ pmax,
    float* __restrict__ scbuf, float* __restrict__ pinv) {
  int b = blockIdx.x, tid = threadIdx.x;
  __shared__ float red[4];
  float mx = -1e30f;
#pragma unroll
  for (int i = 0; i < 8; ++i) mx = fmaxf(mx, pmax[b * 8 + i]);
  float sum = 0.f;
  for (int i = tid; i < KK; i += 256) {
    float e = __expf(scbuf[(size_t)b * KK + i] - mx);
    scbuf[(size_t)b * KK + i] = e;
    sum += e;
  }
  sum = wsum(sum);
  if ((tid & 63) == 0) red[tid >> 6] = sum;
  __syncthreads();
  if (tid == 0) pinv[b] = 1.0f / (red[0] + red[1] + red[2] + red[3]);
}
__global__ __launch_bounds__(256) void attn_vs_k(const float* __restrict__ scbuf,
    const unsigned short* __restrict__ kcvc, float* __restrict__ ppart) {
  int b = blockIdx.x, g = blockIdx.y, tid = threadIdx.x;
  float2 acc = {0.f, 0.f};
  for (int it = 0; it < 256; ++it) {
    int kk = g * 256 + it;
    float wgt = scbuf[(size_t)b * KK + kk];
    ushort2 vu = ((const ushort2*)(kcvc + ((size_t)b * NTOK + 1 + kk) * 1024 + 512))[tid];
    acc.x = fmaf(wgt, b2f(vu.x), acc.x);
    acc.y = fmaf(wgt, b2f(vu.y), acc.y);
  }
  ((float2*)(ppart + ((size_t)b * 8 + g) * DD))[tid] = acc;
}
__global__ __launch_bounds__(256) void attn_red_k(const float* __restrict__ ppart,
    const float* __restrict__ pinv, float* __restrict__ pooled) {
  int b = blockIdx.x, tid = threadIdx.x;
  float inv = pinv[b];
  float2 acc = {0.f, 0.f};
#pragma unroll
  for (int g = 0; g < 8; ++g) {
    float2 p = ((const float2*)(ppart + ((size_t)b * 8 + g) * DD))[tid];
    acc.x += p.x; acc.y += p.y;
  }
  ((float2*)(pooled + (size_t)b * DD))[tid] = make_float2(acc.x * inv, acc.y * inv);
}

// ---------------- final projection, fp32 out ----------------
__global__ __launch_bounds__(256) void out_k(const float* __restrict__ pooled,
    const float* __restrict__ co_w, const float* __restrict__ co_b,
    float* __restrict__ out) {
  int b = blockIdx.x, tid = threadIdx.x;
  __shared__ float ps[DD];
  ((float2*)ps)[tid] = ((const float2*)(pooled + (size_t)b * DD))[tid];
  __syncthreads();
  float a0 = co_b[tid], a1 = co_b[tid + 256];
  for (int d = 0; d < 512; ++d) {
    float p = ps[d];
    a0 = fmaf(p, co_w[(size_t)d * 512 + tid], a0);
    a1 = fmaf(p, co_w[(size_t)d * 512 + tid + 256], a1);
  }
  out[(size_t)b * 512 + tid] = a0;
  out[(size_t)b * 512 + tid + 256] = a1;
}

extern "C" void kernel_launch(void* const* d_in, const int* in_sizes, int n_in,
                              void* d_out, int out_size, void* d_ws, size_t ws_size,
                              hipStream_t stream) {
  const float* expr       = (const float*)d_in[0];
  const float* coords     = (const float*)d_in[1];
  const int*   gene_ids   = (const int*)d_in[2];
  const float* gene_table = (const float*)d_in[3];
  const float* pos_table  = (const float*)d_in[4];
  const float* value_tab  = (const float*)d_in[5];
  const float* sp_w  = (const float*)d_in[6];
  const float* sp_b  = (const float*)d_in[7];
  const float* sp_g  = (const float*)d_in[8];
  const float* sp_bb = (const float*)d_in[9];
  const float* ln1_g = (const float*)d_in[10];
  const float* ln1_b = (const float*)d_in[11];
  const float* qw = (const float*)d_in[12];
  const float* qbias = (const float*)d_in[13];
  const float* kw = (const float*)d_in[14];
  const float* kbias = (const float*)d_in[15];
  const float* vw = (const float*)d_in[16];
  const float* vbias = (const float*)d_in[17];
  const float* ow = (const float*)d_in[18];
  const float* obias = (const float*)d_in[19];
  const float* proj  = (const float*)d_in[20];
  const float* ln2_g = (const float*)d_in[21];
  const float* ln2_b = (const float*)d_in[22];
  const float* ff1w = (const float*)d_in[23];
  const float* ff1b = (const float*)d_in[24];
  const float* ff2w = (const float*)d_in[25];
  const float* ff2b = (const float*)d_in[26];
  const float* cqw = (const float*)d_in[27];
  const float* cqb = (const float*)d_in[28];
  const float* ckw = (const float*)d_in[29];
  const float* ckb = (const float*)d_in[30];
  const float* cvw = (const float*)d_in[31];
  const float* cvb = (const float*)d_in[32];
  const float* cow = (const float*)d_in[33];
  const float* cob = (const float*)d_in[34];
  float* out = (float*)d_out;

  const size_t SZ = (size_t)RTOT * DD;
  const size_t MS = (size_t)DD * DD;
  const size_t FS = (size_t)DD * 4 * DD;
  const size_t LST = 4 * MS + 2 * FS;
  const size_t WBN = 4 * LST + 2 * MS;
  const size_t CTXN = (size_t)BB * NH * 64 * 256;

  float* x = (float*)d_ws;
  unsigned short* KVb = (unsigned short*)(x + SZ);   // 2*SZ: K|V packed -> Q|o -> FFN mid
  unsigned short* Cb = KVb + 2 * SZ;                 // xln bf16
  unsigned short* wb = Cb + SZ;
  unsigned short* ctxTb = wb + WBN;
  unsigned short* projb = ctxTb + CTXN;
  float* kpsum = (float*)(projb + (size_t)NL * MM * DHD);
  float* pooled = kpsum + (size_t)BB * NH * MM;
  float* bmax  = pooled + (size_t)BB * DD;
  float* kmaxg = bmax + 2816;
  float* scbuf = kmaxg + 16;
  float* pmax  = scbuf + (size_t)BB * KK;
  float* pinv  = pmax + 256;
  float* ppart = pinv + 32;
  float* biasKV = ppart + (size_t)BB * 8 * DD;       // (NL+1)*1024
  unsigned short* qcb = (unsigned short*)(biasKV + (size_t)(NL + 1) * 1024);
  size_t need = (size_t)((char*)(qcb + (size_t)BB * DD) - (char*)d_ws) + 256;
  if (ws_size < need) {
    sentinel_k<<<(out_size + 255) / 256, 256, 0, stream>>>(out, out_size);
    return;
  }

  for (int l = 0; l < NL; ++l) {
    unsigned short* wl = wb + l * LST;
    wcvt_k<<<dim3(8, 8), 256, 0, stream>>>(kw + l * MS, wl,          512, 512);
    wcvt_k<<<dim3(8, 8), 256, 0, stream>>>(vw + l * MS, wl + MS,     512, 512);
    wcvt_k<<<dim3(8, 8), 256, 0, stream>>>(qw + l * MS, wl + 2 * MS, 512, 512);
    wcvt_k<<<dim3(8, 8), 256, 0, stream>>>(ow + l * MS, wl + 3 * MS, 512, 512);
    wcvt_k<<<dim3(32, 8), 256, 0, stream>>>(ff1w + l * FS, wl + 4 * MS,      512, 2048);
    wcvt_k<<<dim3(8, 32), 256, 0, stream>>>(ff2w + l * FS, wl + 4 * MS + FS, 2048, 512);
    biaspack_k<<<1, 256, 0, stream>>>(kbias + l * DD, vbias + l * DD, biasKV + l * 1024);
  }
  wcvt_k<<<dim3(8, 8), 256, 0, stream>>>(ckw, wb + 4 * LST,      512, 512);
  wcvt_k<<<dim3(8, 8), 256, 0, stream>>>(cvw, wb + 4 * LST + MS, 512, 512);
  biaspack_k<<<1, 256, 0, stream>>>(ckb, cvb, biasKV + NL * 1024);
  cvt_k<<<32, 256, 0, stream>>>(proj, projb, (size_t)NL * MM * DHD / 8);

  embed_k<<<BB * KK / 2, 256, 0, stream>>>(expr, gene_ids, gene_table, pos_table, value_tab, x);
  sp_k<<<BB, 256, 0, stream>>>(coords, sp_w, sp_b, sp_g, sp_bb, x);

  const int RB = (RTOT + 127) / 128;   // 513
  const int HB = (HROWS + 127) / 128;  // 257
  for (int l = 0; l < NL; ++l) {
    unsigned short* wl = wb + l * LST;
    const unsigned short* pbl = projb + (size_t)l * MM * DHD;
    ln_k<<<RTOT, 128, 0, stream>>>(x, ln1_g + l * DD, ln1_b + l * DD, Cb);
    // fused K|V GEMM -> packed KVb [row][1024]
    gemm_bb<unsigned short, 0><<<dim3(8, RB), 256, 0, stream>>>(Cb, DD,
        wl, biasKV + l * 1024, KVb, 1024, RTOT, DD);
    kmax_k<<<dim3(256, 4), 256, 0, stream>>>(KVb, pbl, bmax);
    maxred_k<<<1, 256, 0, stream>>>(bmax, BB * NH * 4, kmaxg);
    k2_k<<<dim3(256, 4), 256, 0, stream>>>(KVb, pbl, kmaxg, ctxTb, kpsum);
    // Q into freed K-half (cols 0-511)
    gemm_bb<unsigned short, 0><<<dim3(4, RB), 256, 0, stream>>>(Cb, DD,
        wl + 2 * MS, qbias + l * DD, KVb, 1024, RTOT, DD);
    qfeat_k<<<dim3(256, 13), 256, 0, stream>>>(KVb, pbl, ctxTb, kpsum);  // o -> cols 512-1023
    gemm_bb<float, 2><<<dim3(4, RB), 256, 0, stream>>>(KVb + 512, 1024,
        wl + 3 * MS, obias + l * DD, x, DD, RTOT, DD);
    ln_k<<<RTOT, 128, 0, stream>>>(x, ln2_g + l * DD, ln2_b + l * DD, Cb);
    for (int c = 0; c < 2; ++c) {
      gemm_bb<unsigned short, 1><<<dim3(16, HB), 256, 0, stream>>>(Cb + (size_t)c * HROWS * DD, DD,
          wl + 4 * MS, ff1b + (size_t)l * 4 * DD, KVb, 2048, HROWS, DD);
      gemm_bb<float, 2><<<dim3(4, HB), 256, 0, stream>>>(KVb, 2048,
          wl + 4 * MS + FS, ff2b + l * DD, x + (size_t)c * HROWS * DD, DD, HROWS, 2048);
    }
  }
  cvt_k<<<(int)(SZ / 8 / 256), 256, 0, stream>>>(x, Cb, SZ / 8);
  // fused kc|vc -> packed KVb
  gemm_bb<unsigned short, 0><<<dim3(8, RB), 256, 0, stream>>>(Cb, DD,
      wb + 4 * LST, biasKV + NL * 1024, KVb, 1024, RTOT, DD);
  gemm_t<float, unsigned short><<<dim3(8, 1), 256, 0, stream>>>(x, (long)NTOK * DD,
      cqw, cqb, qcb, DD, BB, DD, DD);             // qc (token 0 per batch)
  attn_sc_k<<<dim3(BB, 8), 256, 0, stream>>>(qcb, KVb, scbuf, pmax);
  attn_w_k<<<BB, 256, 0, stream>>>(pmax, scbuf, pinv);
  attn_vs_k<<<dim3(BB, 8), 256, 0, stream>>>(scbuf, KVb, ppart);
  attn_red_k<<<BB, 256, 0, stream>>>(ppart, pinv, pooled);
  out_k<<<BB, 256, 0, stream>>>(pooled, cow, cob, out);
}

// Round 14
// 5420.215 us; speedup vs baseline: 1.1855x; 1.1068x over previous
//
#include <hip/hip_runtime.h>
#include <hip/hip_bf16.h>

#define BB 32
#define KK 2048
#define NTOK 2049
#define DD 512
#define NH 8
#define DHD 64
#define NL 4
#define MM 256
#define RTOT (BB*NTOK)          // 65568
#define HROWS (RTOT/2)          // 32784
#define DN 0.35355339059327373f // 64^-0.25
#define RM 0.0625f              // 256^-0.5
#define EPSK 1e-4f

typedef __attribute__((ext_vector_type(8))) short bf16x8;
typedef __attribute__((ext_vector_type(4))) float f32x4;

__device__ __forceinline__ float wsum(float v) {
#pragma unroll
  for (int o = 32; o; o >>= 1) v += __shfl_xor(v, o);
  return v;
}
__device__ __forceinline__ float wmax(float v) {
#pragma unroll
  for (int o = 32; o; o >>= 1) v = fmaxf(v, __shfl_xor(v, o));
  return v;
}
__device__ __forceinline__ float gelu1(float v) {
  return 0.5f * v * (1.0f + erff(v * 0.70710678118654752f));
}
__device__ __forceinline__ float b2f(unsigned short u) {
  union { unsigned int i; float f; } w; w.i = ((unsigned int)u) << 16; return w.f;
}
__device__ __forceinline__ unsigned short f2b(float f) {
  union { float f; unsigned int i; } w; w.f = f;
  unsigned int r = w.i + 0x7FFFu + ((w.i >> 16) & 1u);
  return (unsigned short)(r >> 16);
}
__device__ __forceinline__ float4 ld4(const float* p) { return *(const float4*)p; }
__device__ __forceinline__ float4 ld4(const unsigned short* p) {
  ushort4 u = *(const ushort4*)p;
  return make_float4(b2f(u.x), b2f(u.y), b2f(u.z), b2f(u.w));
}
__device__ __forceinline__ void st4(float* p, float4 v) { *(float4*)p = v; }
__device__ __forceinline__ void st4(unsigned short* p, float4 v) {
  ushort4 u; u.x = f2b(v.x); u.y = f2b(v.y); u.z = f2b(v.z); u.w = f2b(v.w);
  *(ushort4*)p = u;
}
__device__ __forceinline__ bf16x8 ld8s(const unsigned short* p) {
  union { ushort4 u[2]; bf16x8 v; } w;
  w.u[0] = *(const ushort4*)p;
  w.u[1] = *(const ushort4*)(p + 4);
  return w.v;
}
__device__ __forceinline__ void gload16(const void* g, void* l) {
  __builtin_amdgcn_global_load_lds(
      (const __attribute__((address_space(1))) void*)g,
      (__attribute__((address_space(3))) void*)l, 16, 0, 0);
}

// ---------------- sentinel: ws too small -> absmax ~1.2e4 ----------------
__global__ void sentinel_k(float* out, int n) {
  int i = blockIdx.x * 256 + threadIdx.x;
  if (i < n) out[i] = 12345.0f;
}

// ---------------- bias pack: dst[0..511]=a, dst[512..1023]=b ----------------
__global__ void biaspack_k(const float* __restrict__ a, const float* __restrict__ bsrc,
                           float* __restrict__ dst) {
  int i = threadIdx.x;
  dst[i] = a[i]; dst[i + 256] = a[i + 256];
  dst[512 + i] = bsrc[i]; dst[768 + i] = bsrc[i + 256];
}

// ---------------- weight convert + transpose: Wt[n][k] = bf16(W[k][n]) ----------------
__global__ __launch_bounds__(256) void wcvt_k(const float* __restrict__ W,
    unsigned short* __restrict__ Wt, int Kd, int Cols) {
  __shared__ float Ls[64][65];
  int tid = threadIdx.x;
  int n0 = blockIdx.x * 64, k0 = blockIdx.y * 64;
  int kr = tid >> 2, nseg = (tid & 3) << 4;
#pragma unroll
  for (int u = 0; u < 4; ++u) {
    float4 v = *(const float4*)(W + (size_t)(k0 + kr) * Cols + n0 + nseg + u * 4);
    *(float4*)&Ls[kr][nseg + u * 4] = v;
  }
  __syncthreads();
  int nr = tid >> 2, kseg = (tid & 3) << 4;
  unsigned int pk[8];
#pragma unroll
  for (int i = 0; i < 8; ++i) {
    unsigned short lo = f2b(Ls[kseg + 2 * i][nr]);
    unsigned short hi = f2b(Ls[kseg + 2 * i + 1][nr]);
    pk[i] = (unsigned int)lo | ((unsigned int)hi << 16);
  }
  unsigned short* dst = Wt + (size_t)(n0 + nr) * Kd + k0 + kseg;
  ((uint4*)dst)[0] = make_uint4(pk[0], pk[1], pk[2], pk[3]);
  ((uint4*)dst)[1] = make_uint4(pk[4], pk[5], pk[6], pk[7]);
}

// ---------------- embedding ----------------
__global__ __launch_bounds__(256) void embed_k(const float* __restrict__ expr,
    const int* __restrict__ gene_ids, const float* __restrict__ gene_table,
    const float* __restrict__ pos_table, const float* __restrict__ value_tab,
    float* __restrict__ x) {
  int tok = blockIdx.x * 2 + (threadIdx.x >> 7);
  int t = threadIdx.x & 127;
  int b = tok >> 11;
  int k = tok & 2047;
  float e = expr[tok];
  int bin = (int)(e * 5.0f);
  bin = bin < 0 ? 0 : (bin > 4 ? 4 : bin);
  int g = gene_ids[k];
  float4 a = ((const float4*)(gene_table + (size_t)g * DD))[t];
  float4 p = ((const float4*)(pos_table + (size_t)k * DD))[t];
  float4 vv = ((const float4*)(value_tab + (size_t)bin * DD))[t];
  float4 r;
  r.x = a.x + p.x + vv.x; r.y = a.y + p.y + vv.y;
  r.z = a.z + p.z + vv.z; r.w = a.w + p.w + vv.w;
  ((float4*)(x + ((size_t)b * NTOK + 1 + k) * DD))[t] = r;
}

// ---------------- spatial token ----------------
__global__ __launch_bounds__(256) void sp_k(const float* __restrict__ coords,
    const float* __restrict__ sp_w, const float* __restrict__ sp_b,
    const float* __restrict__ g, const float* __restrict__ bb,
    float* __restrict__ x) {
  int b = blockIdx.x, t = threadIdx.x;
  __shared__ float red[8];
  float c0 = coords[2 * b], c1 = coords[2 * b + 1];
  float v0 = fmaf(c0, sp_w[t],       fmaf(c1, sp_w[512 + t], sp_b[t]));
  float v1 = fmaf(c0, sp_w[t + 256], fmaf(c1, sp_w[768 + t], sp_b[t + 256]));
  float s = wsum(v0 + v1);
  int wid = t >> 6;
  if ((t & 63) == 0) red[wid] = s;
  __syncthreads();
  float mu = (red[0] + red[1] + red[2] + red[3]) * (1.0f / 512.0f);
  float d0 = v0 - mu, d1 = v1 - mu;
  float s2 = wsum(d0 * d0 + d1 * d1);
  if ((t & 63) == 0) red[4 + wid] = s2;
  __syncthreads();
  float var = (red[4] + red[5] + red[6] + red[7]) * (1.0f / 512.0f);
  float rs = rsqrtf(var + 1e-5f);
  float y0 = d0 * rs * g[t] + bb[t];
  float y1 = d1 * rs * g[t + 256] + bb[t + 256];
  x[(size_t)b * NTOK * DD + t] = gelu1(y0);
  x[(size_t)b * NTOK * DD + t + 256] = gelu1(y1);
}

// ---------------- fused LN -> bf16 ----------------
__global__ __launch_bounds__(128) void ln_k(const float* __restrict__ x,
    const float* __restrict__ gamma, const float* __restrict__ beta,
    unsigned short* __restrict__ h) {
  size_t row = blockIdx.x;
  int t = threadIdx.x;
  float4 v = ((const float4*)(x + row * DD))[t];
  float s = v.x + v.y + v.z + v.w;
  float s2 = v.x * v.x + v.y * v.y + v.z * v.z + v.w * v.w;
  __shared__ float red[4];
  float ws1 = wsum(s), ws2 = wsum(s2);
  int wid = t >> 6;
  if ((t & 63) == 0) { red[wid * 2] = ws1; red[wid * 2 + 1] = ws2; }
  __syncthreads();
  float S = red[0] + red[2], S2 = red[1] + red[3];
  float mu = S * (1.0f / 512.0f);
  float var = S2 * (1.0f / 512.0f) - mu * mu;
  float rs = rsqrtf(var + 1e-5f);
  float4 gm = ((const float4*)gamma)[t], bt = ((const float4*)beta)[t];
  float4 o;
  o.x = (v.x - mu) * rs * gm.x + bt.x;
  o.y = (v.y - mu) * rs * gm.y + bt.y;
  o.z = (v.z - mu) * rs * gm.z + bt.z;
  o.w = (v.w - mu) * rs * gm.w + bt.w;
  st4(h + row * DD + t * 4, o);
}

// ---------------- fp32 -> bf16 convert ----------------
__global__ __launch_bounds__(256) void cvt_k(const float* __restrict__ x,
    unsigned short* __restrict__ o, size_t n8) {
  size_t i = (size_t)blockIdx.x * 256 + threadIdx.x;
  if (i >= n8) return;
  float4 a = ((const float4*)x)[2 * i];
  float4 b = ((const float4*)x)[2 * i + 1];
  st4(o + i * 8, a);
  st4(o + i * 8 + 4, b);
}

// ======= all-bf16 MFMA GEMM, BK=64, XOR-swizzled LDS, XCD swizzle,
//         LDS-bounce coalesced epilogue =======
template <typename TC, int FLAGS>
__global__ __launch_bounds__(256) void gemm_bb(const unsigned short* __restrict__ A, long lda,
    const unsigned short* __restrict__ Wt, const float* __restrict__ bias,
    TC* __restrict__ C, int ldc, int R, int Kd) {
  __shared__ unsigned short Sh[128 * 136];   // 34.8 KB; aliases As/Bs and epilogue tile
  unsigned short* As = Sh;                   // [128*64]
  unsigned short* Bs = Sh + 128 * 64;        // [128*64]
  const int tid = threadIdx.x;
  const int lane = tid & 63;
  const int w = tid >> 6;
  const int wr = w >> 1, wc = w & 1;
  const int nwg = gridDim.x * gridDim.y;
  const int orig = blockIdx.y * gridDim.x + blockIdx.x;
  const int qd = nwg >> 3, rm = nwg & 7;
  const int xcd = orig & 7, idx = orig >> 3;
  const int wg = (xcd < rm ? xcd * (qd + 1) : rm * (qd + 1) + (xcd - rm) * qd) + idx;
  const int rblk = (wg / gridDim.x) << 7;
  const int cblk = (wg % gridDim.x) << 7;
  const int m0 = lane & 15, kb = lane >> 4;
  const int lrow8 = lane >> 3;
  const int csw = (((lane & 7) ^ lrow8) << 3);
  f32x4 acc[4][4] = {};
  for (int k0 = 0; k0 < Kd; k0 += 64) {
#pragma unroll
    for (int rd = 0; rd < 4; ++rd) {
      int rg = w * 32 + rd * 8;
      int gra = rblk + rg + lrow8; if (gra >= R) gra = R - 1;
      gload16(A  + (size_t)gra * lda + k0 + csw, &As[rg * 64]);
      gload16(Wt + (size_t)(cblk + rg + lrow8) * Kd + k0 + csw, &Bs[rg * 64]);
    }
    __syncthreads();
    bf16x8 af[2][4], bfr[2][4];
#pragma unroll
    for (int ks = 0; ks < 2; ++ks) {
      int c = (ks << 2) | kb;
#pragma unroll
      for (int mi = 0; mi < 4; ++mi) {
        int ar = wr * 64 + mi * 16 + m0;
        af[ks][mi] = *(const bf16x8*)&As[ar * 64 + ((c ^ (ar & 7)) << 3)];
        int br = wc * 64 + mi * 16 + m0;
        bfr[ks][mi] = *(const bf16x8*)&Bs[br * 64 + ((c ^ (br & 7)) << 3)];
      }
    }
#pragma unroll
    for (int ks = 0; ks < 2; ++ks)
#pragma unroll
      for (int mi = 0; mi < 4; ++mi)
#pragma unroll
        for (int ni = 0; ni < 4; ++ni)
          acc[mi][ni] = __builtin_amdgcn_mfma_f32_16x16x32_bf16(af[ks][mi], bfr[ks][ni], acc[mi][ni], 0, 0, 0);
    __syncthreads();
  }
  const int lrow4 = (lane >> 4) << 2, lcol = lane & 15;
  if constexpr (sizeof(TC) == 2) {
    // ---- bf16 out: stage whole 128x128 tile (stride 136), vector stores ----
#pragma unroll
    for (int mi = 0; mi < 4; ++mi)
#pragma unroll
      for (int reg = 0; reg < 4; ++reg) {
        int rloc = wr * 64 + mi * 16 + lrow4 + reg;
#pragma unroll
        for (int ni = 0; ni < 4; ++ni) {
          int cloc = wc * 64 + ni * 16 + lcol;
          float v = acc[mi][ni][reg] + bias[cblk + cloc];
          if constexpr ((FLAGS & 1) != 0) v = gelu1(v);
          Sh[rloc * 136 + cloc] = f2b(v);
        }
      }
    __syncthreads();
    int rl = tid >> 1;
    int row = rblk + rl;
    if (row < R) {
      unsigned short* cp = (unsigned short*)C + (size_t)row * ldc + cblk;
#pragma unroll
      for (int u = 0; u < 8; ++u) {
        int c = (tid & 1) * 8 + u * 16;
        *(uint4*)(cp + c) = *(const uint4*)&Sh[rl * 136 + c];
      }
    }
  } else {
    // ---- fp32 accumulate: two half-tile passes (stride 132), float4 RMW ----
    float* Sf = (float*)Sh;
#pragma unroll
    for (int p = 0; p < 2; ++p) {
      if (wr == p) {
#pragma unroll
        for (int mi = 0; mi < 4; ++mi)
#pragma unroll
          for (int reg = 0; reg < 4; ++reg) {
            int rloc = mi * 16 + lrow4 + reg;    // 0..63
#pragma unroll
            for (int ni = 0; ni < 4; ++ni) {
              int cloc = wc * 64 + ni * 16 + lcol;
              float v = acc[mi][ni][reg] + bias[cblk + cloc];
              if constexpr ((FLAGS & 1) != 0) v = gelu1(v);
              Sf[rloc * 132 + cloc] = v;
            }
          }
      }
      __syncthreads();
      int rl = tid >> 2;
      int row = rblk + p * 64 + rl;
      if (row < R) {
        float* cp = (float*)C + (size_t)row * ldc + cblk;
#pragma unroll
        for (int u = 0; u < 8; ++u) {
          int c = (tid & 3) * 4 + u * 16;
          float4 nv = *(const float4*)&Sf[rl * 132 + c];
          if constexpr ((FLAGS & 2) != 0) {
            float4 old = *(const float4*)(cp + c);
            nv.x += old.x; nv.y += old.y; nv.z += old.z; nv.w += old.w;
          }
          *(float4*)(cp + c) = nv;
        }
      }
      __syncthreads();
    }
  }
}

// ---------------- fp32 tile GEMM (tiny qc only) ----------------
template <typename TA, typename TC>
__global__ __launch_bounds__(256) void gemm_t(const TA* __restrict__ A, long lda,
    const float* __restrict__ W, const float* __restrict__ bias,
    TC* __restrict__ C, int ldc, int R, int Kd, int Cols) {
  __shared__ float As[16][68];
  __shared__ float Ws[16][64];
  int tid = threadIdx.x;
  int tx = tid & 15, ty = tid >> 4;
  int rblk = blockIdx.y << 6, cblk = blockIdx.x << 6;
  float acc[4][4] = {};
  int lr = tid >> 2, lk = (tid & 3) << 2;
  int wk = tid >> 4, wcc = (tid & 15) << 2;
  int gra = rblk + lr;
  for (int k0 = 0; k0 < Kd; k0 += 16) {
    float4 av = make_float4(0.f, 0.f, 0.f, 0.f);
    if (gra < R) av = ld4(A + (size_t)gra * lda + k0 + lk);
    As[lk][lr] = av.x; As[lk + 1][lr] = av.y; As[lk + 2][lr] = av.z; As[lk + 3][lr] = av.w;
    *(float4*)&Ws[wk][wcc] = *(const float4*)(W + (size_t)(k0 + wk) * Cols + cblk + wcc);
    __syncthreads();
#pragma unroll
    for (int p = 0; p < 16; ++p) {
      float4 a4 = *(const float4*)&As[p][ty << 2];
      float4 b4 = *(const float4*)&Ws[p][tx << 2];
      acc[0][0] = fmaf(a4.x, b4.x, acc[0][0]); acc[0][1] = fmaf(a4.x, b4.y, acc[0][1]);
      acc[0][2] = fmaf(a4.x, b4.z, acc[0][2]); acc[0][3] = fmaf(a4.x, b4.w, acc[0][3]);
      acc[1][0] = fmaf(a4.y, b4.x, acc[1][0]); acc[1][1] = fmaf(a4.y, b4.y, acc[1][1]);
      acc[1][2] = fmaf(a4.y, b4.z, acc[1][2]); acc[1][3] = fmaf(a4.y, b4.w, acc[1][3]);
      acc[2][0] = fmaf(a4.z, b4.x, acc[2][0]); acc[2][1] = fmaf(a4.z, b4.y, acc[2][1]);
      acc[2][2] = fmaf(a4.z, b4.z, acc[2][2]); acc[2][3] = fmaf(a4.z, b4.w, acc[2][3]);
      acc[3][0] = fmaf(a4.w, b4.x, acc[3][0]); acc[3][1] = fmaf(a4.w, b4.y, acc[3][1]);
      acc[3][2] = fmaf(a4.w, b4.z, acc[3][2]); acc[3][3] = fmaf(a4.w, b4.w, acc[3][3]);
    }
    __syncthreads();
  }
  int gcb = cblk + (tx << 2);
  float4 bi = *(const float4*)(bias + gcb);
#pragma unroll
  for (int i = 0; i < 4; ++i) {
    int gr = rblk + (ty << 2) + i;
    if (gr < R) {
      float4 val;
      val.x = acc[i][0] + bi.x; val.y = acc[i][1] + bi.y;
      val.z = acc[i][2] + bi.z; val.w = acc[i][3] + bi.w;
      TC* cp = C + (size_t)gr * ldc + gcb;
      st4(cp, val);
    }
  }
}

// ------- FAVOR key pass 1 (MFMA, packed KV input): max over dd = K@proj^T -------
__global__ __launch_bounds__(256) void kmax_k(const unsigned short* __restrict__ kv,
    const unsigned short* __restrict__ projb, float* __restrict__ bmax) {
  int orig = blockIdx.y * gridDim.x + blockIdx.x;   // grid (256,4) = 1024
  int wg = ((orig & 7) << 7) + (orig >> 3);
  int bh = wg >> 2, gy = wg & 3;
  int b = bh >> 3, hh = bh & 7;
  int tid = threadIdx.x;
  int lane = tid & 63, w = tid >> 6;
  int m0 = lane & 15, kb = lane >> 4;
  __shared__ float red[4];
  bf16x8 bp[4][2];
#pragma unroll
  for (int nf = 0; nf < 4; ++nf)
#pragma unroll
    for (int ks = 0; ks < 2; ++ks)
      bp[nf][ks] = *(const bf16x8*)(projb + (size_t)(w * 64 + nf * 16 + m0) * 64 + ks * 32 + kb * 8);
  const unsigned short* kvb = kv + (size_t)b * NTOK * 1024 + hh * 64;
  float mx = -1e30f;
  for (int t = gy; t < 65; t += 4) {
    int n0 = t * 32;
    bf16x8 aq[2][2];
#pragma unroll
    for (int mi = 0; mi < 2; ++mi) {
      int n = n0 + mi * 16 + m0; if (n >= NTOK) n = NTOK - 1;
#pragma unroll
      for (int ks = 0; ks < 2; ++ks)
        aq[mi][ks] = *(const bf16x8*)(kvb + (size_t)n * 1024 + ks * 32 + kb * 8);
    }
    f32x4 da[2][4] = {};
#pragma unroll
    for (int ks = 0; ks < 2; ++ks)
#pragma unroll
      for (int mi = 0; mi < 2; ++mi)
#pragma unroll
        for (int nf = 0; nf < 4; ++nf)
          da[mi][nf] = __builtin_amdgcn_mfma_f32_16x16x32_bf16(aq[mi][ks], bp[nf][ks], da[mi][nf], 0, 0, 0);
#pragma unroll
    for (int mi = 0; mi < 2; ++mi)
#pragma unroll
      for (int nf = 0; nf < 4; ++nf)
#pragma unroll
        for (int r = 0; r < 4; ++r)
          mx = fmaxf(mx, da[mi][nf][r]);
  }
  mx *= DN;
  mx = wmax(mx);
  if ((tid & 63) == 0) red[tid >> 6] = mx;
  __syncthreads();
  if (tid == 0)
    bmax[(size_t)bh * 4 + gy] = fmaxf(fmaxf(red[0], red[1]), fmaxf(red[2], red[3]));
}

__global__ __launch_bounds__(256) void maxred_k(const float* __restrict__ in, int n,
                                                float* __restrict__ out) {
  float m = -1e30f;
  for (int i = threadIdx.x; i < n; i += 256) m = fmaxf(m, in[i]);
  m = wmax(m);
  __shared__ float red[4];
  if ((threadIdx.x & 63) == 0) red[threadIdx.x >> 6] = m;
  __syncthreads();
  if (threadIdx.x == 0) out[0] = fmaxf(fmaxf(red[0], red[1]), fmaxf(red[2], red[3]));
}

// ===== FAVOR key pass 2 v6 (MFMA, in-register exp, packed KV) =====
__global__ __launch_bounds__(256) void k2_k(const unsigned short* __restrict__ kv,
    const unsigned short* __restrict__ projb,
    const float* __restrict__ kmaxg, unsigned short* __restrict__ ctxTb,
    float* __restrict__ kpsum) {
  int orig = blockIdx.y * gridDim.x + blockIdx.x;   // grid (256,4) = 1024
  int wg = ((orig & 7) << 7) + (orig >> 3);
  int bh = wg >> 2, mg = wg & 3;
  int b = bh >> 3, hh = bh & 7;
  int tid = threadIdx.x;
  int lane = tid & 63, w = tid >> 6;
  int m0 = lane & 15, kb = lane >> 4;
  __shared__ __align__(16) unsigned short kpT[64 * 44];
  __shared__ __align__(16) unsigned short VT[64 * 44];
  float kmax = kmaxg[0];
  bf16x8 bp[2];
#pragma unroll
  for (int ks = 0; ks < 2; ++ks)
    bp[ks] = *(const bf16x8*)(projb + (size_t)(mg * 64 + w * 16 + m0) * 64 + ks * 32 + kb * 8);
  f32x4 acc[4] = {};
  float ksum = 0.f;
  int dv = tid & 63, tq = tid >> 6;
  const unsigned short* kvb = kv + (size_t)b * NTOK * 1024 + hh * 64;
  for (int t = 0; t < 65; ++t) {
    int n0 = t * 32;
    int tlim = NTOK - n0; if (tlim > 32) tlim = 32;
    __syncthreads();
    {
      unsigned int pk[4];
#pragma unroll
      for (int j = 0; j < 8; ++j) {
        int n = n0 + tq * 8 + j; if (n >= NTOK) n = NTOK - 1;
        unsigned int v = kvb[(size_t)n * 1024 + 512 + dv];
        if (j & 1) pk[j >> 1] |= v << 16; else pk[j >> 1] = v;
      }
      *(uint2*)&VT[dv * 44 + tq * 8]     = make_uint2(pk[0], pk[1]);
      *(uint2*)&VT[dv * 44 + tq * 8 + 4] = make_uint2(pk[2], pk[3]);
    }
    bf16x8 aq[2][2];
    float dg[2];
#pragma unroll
    for (int mi = 0; mi < 2; ++mi) {
      int n = n0 + mi * 16 + m0; if (n >= NTOK) n = NTOK - 1;
      float s = 0.f;
#pragma unroll
      for (int ks = 0; ks < 2; ++ks) {
        aq[mi][ks] = *(const bf16x8*)(kvb + (size_t)n * 1024 + ks * 32 + kb * 8);
        const unsigned short* ap = (const unsigned short*)&aq[mi][ks];
#pragma unroll
        for (int j = 0; j < 8; ++j) { float v = b2f(ap[j]); s = fmaf(v, v, s); }
      }
      s += __shfl_xor(s, 16);
      s += __shfl_xor(s, 32);
      dg[mi] = 0.5f * DN * DN * s;
    }
    f32x4 da[2] = {};
#pragma unroll
    for (int ks = 0; ks < 2; ++ks)
#pragma unroll
      for (int mi = 0; mi < 2; ++mi)
        da[mi] = __builtin_amdgcn_mfma_f32_16x16x32_bf16(aq[mi][ks], bp[ks], da[mi], 0, 0, 0);
#pragma unroll
    for (int mi = 0; mi < 2; ++mi) {
      unsigned int pk[2];
#pragma unroll
      for (int r = 0; r < 4; ++r) {
        float dval = __shfl(dg[mi], (kb << 2) | r);
        int tt = mi * 16 + (kb << 2) + r;
        float kp = 0.f;
        if (tt < tlim)
          kp = RM * (__expf(da[mi][r] * DN - dval - kmax) + EPSK);
        ksum += kp;
        unsigned int h = (unsigned int)f2b(kp);
        if (r & 1) pk[r >> 1] |= h << 16; else pk[r >> 1] = h;
      }
      *(uint2*)&kpT[(w * 16 + m0) * 44 + mi * 16 + (kb << 2)] = make_uint2(pk[0], pk[1]);
    }
    __syncthreads();
    bf16x8 af = ld8s(&kpT[(w * 16 + m0) * 44 + kb * 8]);
#pragma unroll
    for (int di = 0; di < 4; ++di) {
      bf16x8 bfv = ld8s(&VT[(di * 16 + m0) * 44 + kb * 8]);
      acc[di] = __builtin_amdgcn_mfma_f32_16x16x32_bf16(af, bfv, acc[di], 0, 0, 0);
    }
  }
  ksum += __shfl_xor(ksum, 16);
  ksum += __shfl_xor(ksum, 32);
  if (kb == 0) kpsum[(size_t)bh * MM + mg * 64 + w * 16 + m0] = ksum;
  unsigned short* cT = ctxTb + (size_t)bh * (64 * 256);
#pragma unroll
  for (int di = 0; di < 4; ++di)
#pragma unroll
    for (int r = 0; r < 4; ++r) {
      int m = mg * 64 + w * 16 + (kb << 2) + r;
      int d = di * 16 + m0;
      cT[d * 256 + m] = f2b(acc[di][r]);
    }
}

// ====== FAVOR query pass (MFMA, packed KV: Q in cols 0-511, o -> cols 512-1023) ======
__global__ __launch_bounds__(256) void qfeat_k(unsigned short* __restrict__ kv,
    const unsigned short* __restrict__ projb,
    const unsigned short* __restrict__ ctxTb,
    const float* __restrict__ kpsum) {
  int orig = blockIdx.y * gridDim.x + blockIdx.x;   // grid (256,13) = 3328
  int wg = ((orig & 7) * 416) + (orig >> 3);
  int bh = wg / 13, gy = wg % 13;
  int b = bh >> 3, hh = bh & 7;
  int tid = threadIdx.x;
  int lane = tid & 63, w = tid >> 6;
  int m0 = lane & 15, kb = lane >> 4;
  __shared__ float ddl[32 * 266];
  __shared__ unsigned short Pb[32 * 264];
  __shared__ float ksum_s[256];
  __shared__ float diag_s[32];
  __shared__ float dinv_s[32];
  ksum_s[tid] = kpsum[(size_t)bh * MM + tid];
  bf16x8 bp[4][2], bc[8];
#pragma unroll
  for (int nf = 0; nf < 4; ++nf)
#pragma unroll
    for (int ks = 0; ks < 2; ++ks)
      bp[nf][ks] = *(const bf16x8*)(projb + (size_t)(w * 64 + nf * 16 + m0) * 64 + ks * 32 + kb * 8);
  const unsigned short* cT = ctxTb + (size_t)bh * (64 * 256);
#pragma unroll
  for (int ks = 0; ks < 8; ++ks)
    bc[ks] = *(const bf16x8*)(cT + (size_t)(w * 16 + m0) * 256 + ks * 32 + kb * 8);
  unsigned short* kvb = kv + (size_t)b * NTOK * 1024 + hh * 64;
  int t8 = tid >> 3, q8 = tid & 7;
  for (int t = gy; t < 65; t += 13) {
    int n0 = t * 32;
    int tlim = NTOK - n0; if (tlim > 32) tlim = 32;
    bf16x8 aq[2][2];
#pragma unroll
    for (int mi = 0; mi < 2; ++mi) {
      int n = n0 + mi * 16 + m0; if (n >= NTOK) n = NTOK - 1;
#pragma unroll
      for (int ks = 0; ks < 2; ++ks)
        aq[mi][ks] = *(const bf16x8*)(kvb + (size_t)n * 1024 + ks * 32 + kb * 8);
    }
#pragma unroll
    for (int mi = 0; mi < 2; ++mi) {
      float s = 0.f;
      const unsigned short* ap = (const unsigned short*)&aq[mi][0];
#pragma unroll
      for (int j = 0; j < 16; ++j) { float v = b2f(ap[j]); s = fmaf(v, v, s); }
      s += __shfl_xor(s, 16); s += __shfl_xor(s, 32);
      if (w == 0 && kb == 0) diag_s[mi * 16 + m0] = 0.5f * DN * DN * s;
    }
    f32x4 da[2][4] = {};
#pragma unroll
    for (int ks = 0; ks < 2; ++ks)
#pragma unroll
      for (int mi = 0; mi < 2; ++mi)
#pragma unroll
        for (int nf = 0; nf < 4; ++nf)
          da[mi][nf] = __builtin_amdgcn_mfma_f32_16x16x32_bf16(aq[mi][ks], bp[nf][ks], da[mi][nf], 0, 0, 0);
#pragma unroll
    for (int mi = 0; mi < 2; ++mi)
#pragma unroll
      for (int nf = 0; nf < 4; ++nf)
#pragma unroll
        for (int r = 0; r < 4; ++r)
          ddl[(mi * 16 + kb * 4 + r) * 266 + w * 64 + nf * 16 + m0] = da[mi][nf][r] * DN;
    __syncthreads();
    float mx = -1e30f;
    if (t8 < tlim) {
      for (int j = 0; j < 32; ++j) mx = fmaxf(mx, ddl[t8 * 266 + q8 + 8 * j]);
    }
    mx = fmaxf(mx, __shfl_xor(mx, 1));
    mx = fmaxf(mx, __shfl_xor(mx, 2));
    mx = fmaxf(mx, __shfl_xor(mx, 4));
    float den = 0.f;
    if (t8 < tlim) {
      float dg = diag_s[t8];
      for (int j = 0; j < 32; ++j) {
        int mm = q8 + 8 * j;
        float e = RM * (__expf(ddl[t8 * 266 + mm] - dg - mx) + EPSK);
        Pb[t8 * 264 + mm] = f2b(e);
        den = fmaf(e, ksum_s[mm], den);
      }
    }
    den += __shfl_xor(den, 1); den += __shfl_xor(den, 2); den += __shfl_xor(den, 4);
    if (q8 == 0 && t8 < tlim) dinv_s[t8] = 1.0f / den;
    __syncthreads();
    f32x4 oa[2] = {};
#pragma unroll
    for (int ks = 0; ks < 8; ++ks)
#pragma unroll
      for (int mi = 0; mi < 2; ++mi) {
        bf16x8 ap = *(const bf16x8*)&Pb[(mi * 16 + m0) * 264 + ks * 32 + kb * 8];
        oa[mi] = __builtin_amdgcn_mfma_f32_16x16x32_bf16(ap, bc[ks], oa[mi], 0, 0, 0);
      }
#pragma unroll
    for (int mi = 0; mi < 2; ++mi)
#pragma unroll
      for (int r = 0; r < 4; ++r) {
        int row = mi * 16 + kb * 4 + r;
        if (row < tlim) {
          kvb[(size_t)(n0 + row) * 1024 + 512 + w * 16 + m0] =
              f2b(oa[mi][r] * dinv_s[row]);
        }
      }
    __syncthreads();
  }
}

// ======= final cross-attention, 4-phase parallel (packed kc|vc) =======
__global__ __launch_bounds__(256) void attn_sc_k(const unsigned short* __restrict__ qc,
    const unsigned short* __restrict__ kcvc, float* __restrict__ scbuf,
    float* __restrict__ pmax) {
  int b = blockIdx.x, g = blockIdx.y, tid = threadIdx.x;
  int w = tid >> 6, lane = tid & 63;
  __shared__ float qs[DD];
  __shared__ float red[4];
  {
    ushort2 qu = ((const ushort2*)(qc + (size_t)b * DD))[tid];
    ((float2*)qs)[tid] = make_float2(b2f(qu.x), b2f(qu.y));
  }
  __syncthreads();
  float mx = -1e30f;
  for (int it = 0; it < 64; ++it) {
    int kk = g * 256 + w * 64 + it;
    const unsigned short* row = kcvc + ((size_t)b * NTOK + 1 + kk) * 1024 + lane * 8;
    float4 r0 = ld4(row), r1 = ld4(row + 4);
    float4 q0 = ((const float4*)qs)[lane * 2], q1 = ((const float4*)qs)[lane * 2 + 1];
    float s = r0.x * q0.x + r0.y * q0.y + r0.z * q0.z + r0.w * q0.w
            + r1.x * q1.x + r1.y * q1.y + r1.z * q1.z + r1.w * q1.w;
    s = wsum(s) * 0.044194173824159216f; // 1/sqrt(512)
    if (lane == 0) scbuf[(size_t)b * KK + kk] = s;
    mx = fmaxf(mx, s);
  }
  if (lane == 0) red[w] = mx;
  __syncthreads();
  if (tid == 0) pmax[b * 8 + g] = fmaxf(fmaxf(red[0], red[1]), fmaxf(red[2], red[3]));
}
__global__ __launch_bounds__(256) void attn_w_k(const float* __restrict__ pmax,
    float* __restrict__ scbuf, float* __restrict__ pinv) {
  int b = blockIdx.x, tid = threadIdx.x;
  __shared__ float red[4];
  float mx = -1e30f;
#pragma unroll
  for (int i = 0; i < 8; ++i) mx = fmaxf(mx, pmax[b * 8 + i]);
  float sum = 0.f;
  for (int i = tid; i < KK; i += 256) {
    float e = __expf(scbuf[(size_t)b * KK + i] - mx);
    scbuf[(size_t)b * KK + i] = e;
    sum += e;
  }
  sum = wsum(sum);
  if ((tid & 63) == 0) red[tid >> 6] = sum;
  __syncthreads();
  if (tid == 0) pinv[b] = 1.0f / (red[0] + red[1] + red[2] + red[3]);
}
__global__ __launch_bounds__(256) void attn_vs_k(const float* __restrict__ scbuf,
    const unsigned short* __restrict__ kcvc, float* __restrict__ ppart) {
  int b = blockIdx.x, g = blockIdx.y, tid = threadIdx.x;
  float2 acc = {0.f, 0.f};
  for (int it = 0; it < 256; ++it) {
    int kk = g * 256 + it;
    float wgt = scbuf[(size_t)b * KK + kk];
    ushort2 vu = ((const ushort2*)(kcvc + ((size_t)b * NTOK + 1 + kk) * 1024 + 512))[tid];
    acc.x = fmaf(wgt, b2f(vu.x), acc.x);
    acc.y = fmaf(wgt, b2f(vu.y), acc.y);
  }
  ((float2*)(ppart + ((size_t)b * 8 + g) * DD))[tid] = acc;
}
__global__ __launch_bounds__(256) void attn_red_k(const float* __restrict__ ppart,
    const float* __restrict__ pinv, float* __restrict__ pooled) {
  int b = blockIdx.x, tid = threadIdx.x;
  float inv = pinv[b];
  float2 acc = {0.f, 0.f};
#pragma unroll
  for (int g = 0; g < 8; ++g) {
    float2 p = ((const float2*)(ppart + ((size_t)b * 8 + g) * DD))[tid];
    acc.x += p.x; acc.y += p.y;
  }
  ((float2*)(pooled + (size_t)b * DD))[tid] = make_float2(acc.x * inv, acc.y * inv);
}

// ---------------- final projection, fp32 out ----------------
__global__ __launch_bounds__(256) void out_k(const float* __restrict__ pooled,
    const float* __restrict__ co_w, const float* __restrict__ co_b,
    float* __restrict__ out) {
  int b = blockIdx.x, tid = threadIdx.x;
  __shared__ float ps[DD];
  ((float2*)ps)[tid] = ((const float2*)(pooled + (size_t)b * DD))[tid];
  __syncthreads();
  float a0 = co_b[tid], a1 = co_b[tid + 256];
  for (int d = 0; d < 512; ++d) {
    float p = ps[d];
    a0 = fmaf(p, co_w[(size_t)d * 512 + tid], a0);
    a1 = fmaf(p, co_w[(size_t)d * 512 + tid + 256], a1);
  }
  out[(size_t)b * 512 + tid] = a0;
  out[(size_t)b * 512 + tid + 256] = a1;
}

extern "C" void kernel_launch(void* const* d_in, const int* in_sizes, int n_in,
                              void* d_out, int out_size, void* d_ws, size_t ws_size,
                              hipStream_t stream) {
  const float* expr       = (const float*)d_in[0];
  const float* coords     = (const float*)d_in[1];
  const int*   gene_ids   = (const int*)d_in[2];
  const float* gene_table = (const float*)d_in[3];
  const float* pos_table  = (const float*)d_in[4];
  const float* value_tab  = (const float*)d_in[5];
  const float* sp_w  = (const float*)d_in[6];
  const float* sp_b  = (const float*)d_in[7];
  const float* sp_g  = (const float*)d_in[8];
  const float* sp_bb = (const float*)d_in[9];
  const float* ln1_g = (const float*)d_in[10];
  const float* ln1_b = (const float*)d_in[11];
  const float* qw = (const float*)d_in[12];
  const float* qbias = (const float*)d_in[13];
  const float* kw = (const float*)d_in[14];
  const float* kbias = (const float*)d_in[15];
  const float* vw = (const float*)d_in[16];
  const float* vbias = (const float*)d_in[17];
  const float* ow = (const float*)d_in[18];
  const float* obias = (const float*)d_in[19];
  const float* proj  = (const float*)d_in[20];
  const float* ln2_g = (const float*)d_in[21];
  const float* ln2_b = (const float*)d_in[22];
  const float* ff1w = (const float*)d_in[23];
  const float* ff1b = (const float*)d_in[24];
  const float* ff2w = (const float*)d_in[25];
  const float* ff2b = (const float*)d_in[26];
  const float* cqw = (const float*)d_in[27];
  const float* cqb = (const float*)d_in[28];
  const float* ckw = (const float*)d_in[29];
  const float* ckb = (const float*)d_in[30];
  const float* cvw = (const float*)d_in[31];
  const float* cvb = (const float*)d_in[32];
  const float* cow = (const float*)d_in[33];
  const float* cob = (const float*)d_in[34];
  float* out = (float*)d_out;

  const size_t SZ = (size_t)RTOT * DD;
  const size_t MS = (size_t)DD * DD;
  const size_t FS = (size_t)DD * 4 * DD;
  const size_t LST = 4 * MS + 2 * FS;
  const size_t WBN = 4 * LST + 2 * MS;
  const size_t CTXN = (size_t)BB * NH * 64 * 256;

  float* x = (float*)d_ws;
  unsigned short* KVb = (unsigned short*)(x + SZ);   // 2*SZ: K|V packed -> Q|o -> FFN mid
  unsigned short* Cb = KVb + 2 * SZ;                 // xln bf16
  unsigned short* wb = Cb + SZ;
  unsigned short* ctxTb = wb + WBN;
  unsigned short* projb = ctxTb + CTXN;
  float* kpsum = (float*)(projb + (size_t)NL * MM * DHD);
  float* pooled = kpsum + (size_t)BB * NH * MM;
  float* bmax  = pooled + (size_t)BB * DD;
  float* kmaxg = bmax + 2816;
  float* scbuf = kmaxg + 16;
  float* pmax  = scbuf + (size_t)BB * KK;
  float* pinv  = pmax + 256;
  float* ppart = pinv + 32;
  float* biasKV = ppart + (size_t)BB * 8 * DD;       // (NL+1)*1024
  unsigned short* qcb = (unsigned short*)(biasKV + (size_t)(NL + 1) * 1024);
  size_t need = (size_t)((char*)(qcb + (size_t)BB * DD) - (char*)d_ws) + 256;
  if (ws_size < need) {
    sentinel_k<<<(out_size + 255) / 256, 256, 0, stream>>>(out, out_size);
    return;
  }

  for (int l = 0; l < NL; ++l) {
    unsigned short* wl = wb + l * LST;
    wcvt_k<<<dim3(8, 8), 256, 0, stream>>>(kw + l * MS, wl,          512, 512);
    wcvt_k<<<dim3(8, 8), 256, 0, stream>>>(vw + l * MS, wl + MS,     512, 512);
    wcvt_k<<<dim3(8, 8), 256, 0, stream>>>(qw + l * MS, wl + 2 * MS, 512, 512);
    wcvt_k<<<dim3(8, 8), 256, 0, stream>>>(ow + l * MS, wl + 3 * MS, 512, 512);
    wcvt_k<<<dim3(32, 8), 256, 0, stream>>>(ff1w + l * FS, wl + 4 * MS,      512, 2048);
    wcvt_k<<<dim3(8, 32), 256, 0, stream>>>(ff2w + l * FS, wl + 4 * MS + FS, 2048, 512);
    biaspack_k<<<1, 256, 0, stream>>>(kbias + l * DD, vbias + l * DD, biasKV + l * 1024);
  }
  wcvt_k<<<dim3(8, 8), 256, 0, stream>>>(ckw, wb + 4 * LST,      512, 512);
  wcvt_k<<<dim3(8, 8), 256, 0, stream>>>(cvw, wb + 4 * LST + MS, 512, 512);
  biaspack_k<<<1, 256, 0, stream>>>(ckb, cvb, biasKV + NL * 1024);
  cvt_k<<<32, 256, 0, stream>>>(proj, projb, (size_t)NL * MM * DHD / 8);

  embed_k<<<BB * KK / 2, 256, 0, stream>>>(expr, gene_ids, gene_table, pos_table, value_tab, x);
  sp_k<<<BB, 256, 0, stream>>>(coords, sp_w, sp_b, sp_g, sp_bb, x);

  const int RB = (RTOT + 127) / 128;   // 513
  const int HB = (HROWS + 127) / 128;  // 257
  for (int l = 0; l < NL; ++l) {
    unsigned short* wl = wb + l * LST;
    const unsigned short* pbl = projb + (size_t)l * MM * DHD;
    ln_k<<<RTOT, 128, 0, stream>>>(x, ln1_g + l * DD, ln1_b + l * DD, Cb);
    gemm_bb<unsigned short, 0><<<dim3(8, RB), 256, 0, stream>>>(Cb, DD,
        wl, biasKV + l * 1024, KVb, 1024, RTOT, DD);
    kmax_k<<<dim3(256, 4), 256, 0, stream>>>(KVb, pbl, bmax);
    maxred_k<<<1, 256, 0, stream>>>(bmax, BB * NH * 4, kmaxg);
    k2_k<<<dim3(256, 4), 256, 0, stream>>>(KVb, pbl, kmaxg, ctxTb, kpsum);
    gemm_bb<unsigned short, 0><<<dim3(4, RB), 256, 0, stream>>>(Cb, DD,
        wl + 2 * MS, qbias + l * DD, KVb, 1024, RTOT, DD);
    qfeat_k<<<dim3(256, 13), 256, 0, stream>>>(KVb, pbl, ctxTb, kpsum);
    gemm_bb<float, 2><<<dim3(4, RB), 256, 0, stream>>>(KVb + 512, 1024,
        wl + 3 * MS, obias + l * DD, x, DD, RTOT, DD);
    ln_k<<<RTOT, 128, 0, stream>>>(x, ln2_g + l * DD, ln2_b + l * DD, Cb);
    for (int c = 0; c < 2; ++c) {
      gemm_bb<unsigned short, 1><<<dim3(16, HB), 256, 0, stream>>>(Cb + (size_t)c * HROWS * DD, DD,
          wl + 4 * MS, ff1b + (size_t)l * 4 * DD, KVb, 2048, HROWS, DD);
      gemm_bb<float, 2><<<dim3(4, HB), 256, 0, stream>>>(KVb, 2048,
          wl + 4 * MS + FS, ff2b + l * DD, x + (size_t)c * HROWS * DD, DD, HROWS, 2048);
    }
  }
  cvt_k<<<(int)(SZ / 8 / 256), 256, 0, stream>>>(x, Cb, SZ / 8);
  gemm_bb<unsigned short, 0><<<dim3(8, RB), 256, 0, stream>>>(Cb, DD,
      wb + 4 * LST, biasKV + NL * 1024, KVb, 1024, RTOT, DD);
  gemm_t<float, unsigned short><<<dim3(8, 1), 256, 0, stream>>>(x, (long)NTOK * DD,
      cqw, cqb, qcb, DD, BB, DD, DD);
  attn_sc_k<<<dim3(BB, 8), 256, 0, stream>>>(qcb, KVb, scbuf, pmax);
  attn_w_k<<<BB, 256, 0, stream>>>(pmax, scbuf, pinv);
  attn_vs_k<<<dim3(BB, 8), 256, 0, stream>>>(scbuf, KVb, ppart);
  attn_red_k<<<BB, 256, 0, stream>>>(ppart, pinv, pooled);
  out_k<<<BB, 256, 0, stream>>>(pooled, cow, cob, out);
}

// Round 15
// 5058.336 us; speedup vs baseline: 1.2703x; 1.0715x over previous
//
#include <hip/hip_runtime.h>
#include <hip/hip_bf16.h>

#define BB 32
#define KK 2048
#define NTOK 2049
#define DD 512
#define NH 8
#define DHD 64
#define NL 4
#define MM 256
#define RTOT (BB*NTOK)          // 65568
#define HROWS (RTOT/2)          // 32784
#define DN 0.35355339059327373f // 64^-0.25
#define RM 0.0625f              // 256^-0.5
#define EPSK 1e-4f

typedef __attribute__((ext_vector_type(8))) short bf16x8;
typedef __attribute__((ext_vector_type(4))) float f32x4;

__device__ __forceinline__ float wsum(float v) {
#pragma unroll
  for (int o = 32; o; o >>= 1) v += __shfl_xor(v, o);
  return v;
}
__device__ __forceinline__ float wmax(float v) {
#pragma unroll
  for (int o = 32; o; o >>= 1) v = fmaxf(v, __shfl_xor(v, o));
  return v;
}
__device__ __forceinline__ float gelu1(float v) {
  return 0.5f * v * (1.0f + erff(v * 0.70710678118654752f));
}
__device__ __forceinline__ float b2f(unsigned short u) {
  union { unsigned int i; float f; } w; w.i = ((unsigned int)u) << 16; return w.f;
}
__device__ __forceinline__ unsigned short f2b(float f) {
  union { float f; unsigned int i; } w; w.f = f;
  unsigned int r = w.i + 0x7FFFu + ((w.i >> 16) & 1u);
  return (unsigned short)(r >> 16);
}
__device__ __forceinline__ float4 ld4(const float* p) { return *(const float4*)p; }
__device__ __forceinline__ float4 ld4(const unsigned short* p) {
  ushort4 u = *(const ushort4*)p;
  return make_float4(b2f(u.x), b2f(u.y), b2f(u.z), b2f(u.w));
}
__device__ __forceinline__ void st4(float* p, float4 v) { *(float4*)p = v; }
__device__ __forceinline__ void st4(unsigned short* p, float4 v) {
  ushort4 u; u.x = f2b(v.x); u.y = f2b(v.y); u.z = f2b(v.z); u.w = f2b(v.w);
  *(ushort4*)p = u;
}
__device__ __forceinline__ bf16x8 ld8s(const unsigned short* p) {
  union { ushort4 u[2]; bf16x8 v; } w;
  w.u[0] = *(const ushort4*)p;
  w.u[1] = *(const ushort4*)(p + 4);
  return w.v;
}
__device__ __forceinline__ void gload16(const void* g, void* l) {
  __builtin_amdgcn_global_load_lds(
      (const __attribute__((address_space(1))) void*)g,
      (__attribute__((address_space(3))) void*)l, 16, 0, 0);
}

// ---------------- sentinel: ws too small -> absmax ~1.2e4 ----------------
__global__ void sentinel_k(float* out, int n) {
  int i = blockIdx.x * 256 + threadIdx.x;
  if (i < n) out[i] = 12345.0f;
}

// ---------------- bias pack (2-wide, 1024) ----------------
__global__ void biaspack_k(const float* __restrict__ a, const float* __restrict__ bsrc,
                           float* __restrict__ dst) {
  int i = threadIdx.x;
  dst[i] = a[i]; dst[i + 256] = a[i + 256];
  dst[512 + i] = bsrc[i]; dst[768 + i] = bsrc[i + 256];
}
// ---------------- bias pack (3-wide, 1536: k|v|q) ----------------
__global__ void biaspack3_k(const float* __restrict__ a, const float* __restrict__ bsrc,
                            const float* __restrict__ c, float* __restrict__ dst) {
  int i = threadIdx.x;
  dst[i] = a[i]; dst[i + 256] = a[i + 256];
  dst[512 + i] = bsrc[i]; dst[768 + i] = bsrc[i + 256];
  dst[1024 + i] = c[i]; dst[1280 + i] = c[i + 256];
}

// ---------------- weight convert + transpose: Wt[n][k] = bf16(W[k][n]) ----------------
__global__ __launch_bounds__(256) void wcvt_k(const float* __restrict__ W,
    unsigned short* __restrict__ Wt, int Kd, int Cols) {
  __shared__ float Ls[64][65];
  int tid = threadIdx.x;
  int n0 = blockIdx.x * 64, k0 = blockIdx.y * 64;
  int kr = tid >> 2, nseg = (tid & 3) << 4;
#pragma unroll
  for (int u = 0; u < 4; ++u) {
    float4 v = *(const float4*)(W + (size_t)(k0 + kr) * Cols + n0 + nseg + u * 4);
    *(float4*)&Ls[kr][nseg + u * 4] = v;
  }
  __syncthreads();
  int nr = tid >> 2, kseg = (tid & 3) << 4;
  unsigned int pk[8];
#pragma unroll
  for (int i = 0; i < 8; ++i) {
    unsigned short lo = f2b(Ls[kseg + 2 * i][nr]);
    unsigned short hi = f2b(Ls[kseg + 2 * i + 1][nr]);
    pk[i] = (unsigned int)lo | ((unsigned int)hi << 16);
  }
  unsigned short* dst = Wt + (size_t)(n0 + nr) * Kd + k0 + kseg;
  ((uint4*)dst)[0] = make_uint4(pk[0], pk[1], pk[2], pk[3]);
  ((uint4*)dst)[1] = make_uint4(pk[4], pk[5], pk[6], pk[7]);
}

// ---------------- embedding (bf16 residual) ----------------
__global__ __launch_bounds__(256) void embed_k(const float* __restrict__ expr,
    const int* __restrict__ gene_ids, const float* __restrict__ gene_table,
    const float* __restrict__ pos_table, const float* __restrict__ value_tab,
    unsigned short* __restrict__ x) {
  int tok = blockIdx.x * 2 + (threadIdx.x >> 7);
  int t = threadIdx.x & 127;
  int b = tok >> 11;
  int k = tok & 2047;
  float e = expr[tok];
  int bin = (int)(e * 5.0f);
  bin = bin < 0 ? 0 : (bin > 4 ? 4 : bin);
  int g = gene_ids[k];
  float4 a = ((const float4*)(gene_table + (size_t)g * DD))[t];
  float4 p = ((const float4*)(pos_table + (size_t)k * DD))[t];
  float4 vv = ((const float4*)(value_tab + (size_t)bin * DD))[t];
  float4 r;
  r.x = a.x + p.x + vv.x; r.y = a.y + p.y + vv.y;
  r.z = a.z + p.z + vv.z; r.w = a.w + p.w + vv.w;
  st4(x + ((size_t)b * NTOK + 1 + k) * DD + t * 4, r);
}

// ---------------- spatial token (bf16 out) ----------------
__global__ __launch_bounds__(256) void sp_k(const float* __restrict__ coords,
    const float* __restrict__ sp_w, const float* __restrict__ sp_b,
    const float* __restrict__ g, const float* __restrict__ bb,
    unsigned short* __restrict__ x) {
  int b = blockIdx.x, t = threadIdx.x;
  __shared__ float red[8];
  float c0 = coords[2 * b], c1 = coords[2 * b + 1];
  float v0 = fmaf(c0, sp_w[t],       fmaf(c1, sp_w[512 + t], sp_b[t]));
  float v1 = fmaf(c0, sp_w[t + 256], fmaf(c1, sp_w[768 + t], sp_b[t + 256]));
  float s = wsum(v0 + v1);
  int wid = t >> 6;
  if ((t & 63) == 0) red[wid] = s;
  __syncthreads();
  float mu = (red[0] + red[1] + red[2] + red[3]) * (1.0f / 512.0f);
  float d0 = v0 - mu, d1 = v1 - mu;
  float s2 = wsum(d0 * d0 + d1 * d1);
  if ((t & 63) == 0) red[4 + wid] = s2;
  __syncthreads();
  float var = (red[4] + red[5] + red[6] + red[7]) * (1.0f / 512.0f);
  float rs = rsqrtf(var + 1e-5f);
  float y0 = d0 * rs * g[t] + bb[t];
  float y1 = d1 * rs * g[t + 256] + bb[t + 256];
  x[(size_t)b * NTOK * DD + t] = f2b(gelu1(y0));
  x[(size_t)b * NTOK * DD + t + 256] = f2b(gelu1(y1));
}

// ---------------- fused LN: bf16 x -> bf16 h ----------------
__global__ __launch_bounds__(128) void ln_k(const unsigned short* __restrict__ x,
    const float* __restrict__ gamma, const float* __restrict__ beta,
    unsigned short* __restrict__ h) {
  size_t row = blockIdx.x;
  int t = threadIdx.x;
  float4 v = ld4(x + row * DD + t * 4);
  float s = v.x + v.y + v.z + v.w;
  float s2 = v.x * v.x + v.y * v.y + v.z * v.z + v.w * v.w;
  __shared__ float red[4];
  float ws1 = wsum(s), ws2 = wsum(s2);
  int wid = t >> 6;
  if ((t & 63) == 0) { red[wid * 2] = ws1; red[wid * 2 + 1] = ws2; }
  __syncthreads();
  float S = red[0] + red[2], S2 = red[1] + red[3];
  float mu = S * (1.0f / 512.0f);
  float var = S2 * (1.0f / 512.0f) - mu * mu;
  float rs = rsqrtf(var + 1e-5f);
  float4 gm = ((const float4*)gamma)[t], bt = ((const float4*)beta)[t];
  float4 o;
  o.x = (v.x - mu) * rs * gm.x + bt.x;
  o.y = (v.y - mu) * rs * gm.y + bt.y;
  o.z = (v.z - mu) * rs * gm.z + bt.z;
  o.w = (v.w - mu) * rs * gm.w + bt.w;
  st4(h + row * DD + t * 4, o);
}

// ======= all-bf16 MFMA GEMM, BK=64, XOR-swizzled LDS, XCD swizzle,
//         LDS-bounce coalesced epilogue (bf16 / bf16-RMW / fp32-RMW) =======
template <typename TC, int FLAGS>
__global__ __launch_bounds__(256) void gemm_bb(const unsigned short* __restrict__ A, long lda,
    const unsigned short* __restrict__ Wt, const float* __restrict__ bias,
    TC* __restrict__ C, int ldc, int R, int Kd) {
  __shared__ unsigned short Sh[128 * 136];   // 34.8 KB; aliases As/Bs and epilogue tile
  unsigned short* As = Sh;
  unsigned short* Bs = Sh + 128 * 64;
  const int tid = threadIdx.x;
  const int lane = tid & 63;
  const int w = tid >> 6;
  const int wr = w >> 1, wc = w & 1;
  const int nwg = gridDim.x * gridDim.y;
  const int orig = blockIdx.y * gridDim.x + blockIdx.x;
  const int qd = nwg >> 3, rm = nwg & 7;
  const int xcd = orig & 7, idx = orig >> 3;
  const int wg = (xcd < rm ? xcd * (qd + 1) : rm * (qd + 1) + (xcd - rm) * qd) + idx;
  const int rblk = (wg / gridDim.x) << 7;
  const int cblk = (wg % gridDim.x) << 7;
  const int m0 = lane & 15, kb = lane >> 4;
  const int lrow8 = lane >> 3;
  const int csw = (((lane & 7) ^ lrow8) << 3);
  f32x4 acc[4][4] = {};
  for (int k0 = 0; k0 < Kd; k0 += 64) {
#pragma unroll
    for (int rd = 0; rd < 4; ++rd) {
      int rg = w * 32 + rd * 8;
      int gra = rblk + rg + lrow8; if (gra >= R) gra = R - 1;
      gload16(A  + (size_t)gra * lda + k0 + csw, &As[rg * 64]);
      gload16(Wt + (size_t)(cblk + rg + lrow8) * Kd + k0 + csw, &Bs[rg * 64]);
    }
    __syncthreads();
    bf16x8 af[2][4], bfr[2][4];
#pragma unroll
    for (int ks = 0; ks < 2; ++ks) {
      int c = (ks << 2) | kb;
#pragma unroll
      for (int mi = 0; mi < 4; ++mi) {
        int ar = wr * 64 + mi * 16 + m0;
        af[ks][mi] = *(const bf16x8*)&As[ar * 64 + ((c ^ (ar & 7)) << 3)];
        int br = wc * 64 + mi * 16 + m0;
        bfr[ks][mi] = *(const bf16x8*)&Bs[br * 64 + ((c ^ (br & 7)) << 3)];
      }
    }
#pragma unroll
    for (int ks = 0; ks < 2; ++ks)
#pragma unroll
      for (int mi = 0; mi < 4; ++mi)
#pragma unroll
        for (int ni = 0; ni < 4; ++ni)
          acc[mi][ni] = __builtin_amdgcn_mfma_f32_16x16x32_bf16(af[ks][mi], bfr[ks][ni], acc[mi][ni], 0, 0, 0);
    __syncthreads();
  }
  const int lrow4 = (lane >> 4) << 2, lcol = lane & 15;
  if constexpr (sizeof(TC) == 2 && (FLAGS & 2) == 0) {
    // ---- bf16 out (no accumulate): stage whole tile, uint4 stores ----
#pragma unroll
    for (int mi = 0; mi < 4; ++mi)
#pragma unroll
      for (int reg = 0; reg < 4; ++reg) {
        int rloc = wr * 64 + mi * 16 + lrow4 + reg;
#pragma unroll
        for (int ni = 0; ni < 4; ++ni) {
          int cloc = wc * 64 + ni * 16 + lcol;
          float v = acc[mi][ni][reg] + bias[cblk + cloc];
          if constexpr ((FLAGS & 1) != 0) v = gelu1(v);
          Sh[rloc * 136 + cloc] = f2b(v);
        }
      }
    __syncthreads();
    int rl = tid >> 1;
    int row = rblk + rl;
    if (row < R) {
      unsigned short* cp = (unsigned short*)C + (size_t)row * ldc + cblk;
#pragma unroll
      for (int u = 0; u < 8; ++u) {
        int c = (tid & 1) * 8 + u * 16;
        *(uint4*)(cp + c) = *(const uint4*)&Sh[rl * 136 + c];
      }
    }
  } else {
    // ---- fp32 staging, two half-tile passes; store fp32-RMW or bf16-RMW ----
    float* Sf = (float*)Sh;
#pragma unroll
    for (int p = 0; p < 2; ++p) {
      if (wr == p) {
#pragma unroll
        for (int mi = 0; mi < 4; ++mi)
#pragma unroll
          for (int reg = 0; reg < 4; ++reg) {
            int rloc = mi * 16 + lrow4 + reg;
#pragma unroll
            for (int ni = 0; ni < 4; ++ni) {
              int cloc = wc * 64 + ni * 16 + lcol;
              float v = acc[mi][ni][reg] + bias[cblk + cloc];
              if constexpr ((FLAGS & 1) != 0) v = gelu1(v);
              Sf[rloc * 132 + cloc] = v;
            }
          }
      }
      __syncthreads();
      int rl = tid >> 2;
      int row = rblk + p * 64 + rl;
      if (row < R) {
        if constexpr (sizeof(TC) == 4) {
          float* cp = (float*)C + (size_t)row * ldc + cblk;
#pragma unroll
          for (int u = 0; u < 8; ++u) {
            int c = (tid & 3) * 4 + u * 16;
            float4 nv = *(const float4*)&Sf[rl * 132 + c];
            if constexpr ((FLAGS & 2) != 0) {
              float4 old = *(const float4*)(cp + c);
              nv.x += old.x; nv.y += old.y; nv.z += old.z; nv.w += old.w;
            }
            *(float4*)(cp + c) = nv;
          }
        } else {
          unsigned short* cp = (unsigned short*)C + (size_t)row * ldc + cblk;
#pragma unroll
          for (int u = 0; u < 8; ++u) {
            int c = (tid & 3) * 4 + u * 16;
            float4 nv = *(const float4*)&Sf[rl * 132 + c];
            ushort4 old = *(const ushort4*)(cp + c);
            ushort4 nw;
            nw.x = f2b(nv.x + b2f(old.x)); nw.y = f2b(nv.y + b2f(old.y));
            nw.z = f2b(nv.z + b2f(old.z)); nw.w = f2b(nv.w + b2f(old.w));
            *(ushort4*)(cp + c) = nw;
          }
        }
      }
      __syncthreads();
    }
  }
}

// ---------------- fp32 tile GEMM (tiny qc only; bf16 A, bf16 C) ----------------
template <typename TA, typename TC>
__global__ __launch_bounds__(256) void gemm_t(const TA* __restrict__ A, long lda,
    const float* __restrict__ W, const float* __restrict__ bias,
    TC* __restrict__ C, int ldc, int R, int Kd, int Cols) {
  __shared__ float As[16][68];
  __shared__ float Ws[16][64];
  int tid = threadIdx.x;
  int tx = tid & 15, ty = tid >> 4;
  int rblk = blockIdx.y << 6, cblk = blockIdx.x << 6;
  float acc[4][4] = {};
  int lr = tid >> 2, lk = (tid & 3) << 2;
  int wk = tid >> 4, wcc = (tid & 15) << 2;
  int gra = rblk + lr;
  for (int k0 = 0; k0 < Kd; k0 += 16) {
    float4 av = make_float4(0.f, 0.f, 0.f, 0.f);
    if (gra < R) av = ld4(A + (size_t)gra * lda + k0 + lk);
    As[lk][lr] = av.x; As[lk + 1][lr] = av.y; As[lk + 2][lr] = av.z; As[lk + 3][lr] = av.w;
    *(float4*)&Ws[wk][wcc] = *(const float4*)(W + (size_t)(k0 + wk) * Cols + cblk + wcc);
    __syncthreads();
#pragma unroll
    for (int p = 0; p < 16; ++p) {
      float4 a4 = *(const float4*)&As[p][ty << 2];
      float4 b4 = *(const float4*)&Ws[p][tx << 2];
      acc[0][0] = fmaf(a4.x, b4.x, acc[0][0]); acc[0][1] = fmaf(a4.x, b4.y, acc[0][1]);
      acc[0][2] = fmaf(a4.x, b4.z, acc[0][2]); acc[0][3] = fmaf(a4.x, b4.w, acc[0][3]);
      acc[1][0] = fmaf(a4.y, b4.x, acc[1][0]); acc[1][1] = fmaf(a4.y, b4.y, acc[1][1]);
      acc[1][2] = fmaf(a4.y, b4.z, acc[1][2]); acc[1][3] = fmaf(a4.y, b4.w, acc[1][3]);
      acc[2][0] = fmaf(a4.z, b4.x, acc[2][0]); acc[2][1] = fmaf(a4.z, b4.y, acc[2][1]);
      acc[2][2] = fmaf(a4.z, b4.z, acc[2][2]); acc[2][3] = fmaf(a4.z, b4.w, acc[2][3]);
      acc[3][0] = fmaf(a4.w, b4.x, acc[3][0]); acc[3][1] = fmaf(a4.w, b4.y, acc[3][1]);
      acc[3][2] = fmaf(a4.w, b4.z, acc[3][2]); acc[3][3] = fmaf(a4.w, b4.w, acc[3][3]);
    }
    __syncthreads();
  }
  int gcb = cblk + (tx << 2);
  float4 bi = *(const float4*)(bias + gcb);
#pragma unroll
  for (int i = 0; i < 4; ++i) {
    int gr = rblk + (ty << 2) + i;
    if (gr < R) {
      float4 val;
      val.x = acc[i][0] + bi.x; val.y = acc[i][1] + bi.y;
      val.z = acc[i][2] + bi.z; val.w = acc[i][3] + bi.w;
      TC* cp = C + (size_t)gr * ldc + gcb;
      st4(cp, val);
    }
  }
}

// ------- FAVOR key pass 1 (MFMA, KVQ input stride 1536) -------
__global__ __launch_bounds__(256) void kmax_k(const unsigned short* __restrict__ kv,
    const unsigned short* __restrict__ projb, float* __restrict__ bmax) {
  int orig = blockIdx.y * gridDim.x + blockIdx.x;   // grid (256,4) = 1024
  int wg = ((orig & 7) << 7) + (orig >> 3);
  int bh = wg >> 2, gy = wg & 3;
  int b = bh >> 3, hh = bh & 7;
  int tid = threadIdx.x;
  int lane = tid & 63, w = tid >> 6;
  int m0 = lane & 15, kb = lane >> 4;
  __shared__ float red[4];
  bf16x8 bp[4][2];
#pragma unroll
  for (int nf = 0; nf < 4; ++nf)
#pragma unroll
    for (int ks = 0; ks < 2; ++ks)
      bp[nf][ks] = *(const bf16x8*)(projb + (size_t)(w * 64 + nf * 16 + m0) * 64 + ks * 32 + kb * 8);
  const unsigned short* kvb = kv + (size_t)b * NTOK * 1536 + hh * 64;
  float mx = -1e30f;
  for (int t = gy; t < 65; t += 4) {
    int n0 = t * 32;
    bf16x8 aq[2][2];
#pragma unroll
    for (int mi = 0; mi < 2; ++mi) {
      int n = n0 + mi * 16 + m0; if (n >= NTOK) n = NTOK - 1;
#pragma unroll
      for (int ks = 0; ks < 2; ++ks)
        aq[mi][ks] = *(const bf16x8*)(kvb + (size_t)n * 1536 + ks * 32 + kb * 8);
    }
    f32x4 da[2][4] = {};
#pragma unroll
    for (int ks = 0; ks < 2; ++ks)
#pragma unroll
      for (int mi = 0; mi < 2; ++mi)
#pragma unroll
        for (int nf = 0; nf < 4; ++nf)
          da[mi][nf] = __builtin_amdgcn_mfma_f32_16x16x32_bf16(aq[mi][ks], bp[nf][ks], da[mi][nf], 0, 0, 0);
#pragma unroll
    for (int mi = 0; mi < 2; ++mi)
#pragma unroll
      for (int nf = 0; nf < 4; ++nf)
#pragma unroll
        for (int r = 0; r < 4; ++r)
          mx = fmaxf(mx, da[mi][nf][r]);
  }
  mx *= DN;
  mx = wmax(mx);
  if ((tid & 63) == 0) red[tid >> 6] = mx;
  __syncthreads();
  if (tid == 0)
    bmax[(size_t)bh * 4 + gy] = fmaxf(fmaxf(red[0], red[1]), fmaxf(red[2], red[3]));
}

__global__ __launch_bounds__(256) void maxred_k(const float* __restrict__ in, int n,
                                                float* __restrict__ out) {
  float m = -1e30f;
  for (int i = threadIdx.x; i < n; i += 256) m = fmaxf(m, in[i]);
  m = wmax(m);
  __shared__ float red[4];
  if ((threadIdx.x & 63) == 0) red[threadIdx.x >> 6] = m;
  __syncthreads();
  if (threadIdx.x == 0) out[0] = fmaxf(fmaxf(red[0], red[1]), fmaxf(red[2], red[3]));
}

// ===== FAVOR key pass 2 (MFMA, in-register exp, KVQ stride 1536) =====
__global__ __launch_bounds__(256) void k2_k(const unsigned short* __restrict__ kv,
    const unsigned short* __restrict__ projb,
    const float* __restrict__ kmaxg, unsigned short* __restrict__ ctxTb,
    float* __restrict__ kpsum) {
  int orig = blockIdx.y * gridDim.x + blockIdx.x;   // grid (256,4) = 1024
  int wg = ((orig & 7) << 7) + (orig >> 3);
  int bh = wg >> 2, mg = wg & 3;
  int b = bh >> 3, hh = bh & 7;
  int tid = threadIdx.x;
  int lane = tid & 63, w = tid >> 6;
  int m0 = lane & 15, kb = lane >> 4;
  __shared__ __align__(16) unsigned short kpT[64 * 44];
  __shared__ __align__(16) unsigned short VT[64 * 44];
  float kmax = kmaxg[0];
  bf16x8 bp[2];
#pragma unroll
  for (int ks = 0; ks < 2; ++ks)
    bp[ks] = *(const bf16x8*)(projb + (size_t)(mg * 64 + w * 16 + m0) * 64 + ks * 32 + kb * 8);
  f32x4 acc[4] = {};
  float ksum = 0.f;
  int dv = tid & 63, tq = tid >> 6;
  const unsigned short* kvb = kv + (size_t)b * NTOK * 1536 + hh * 64;
  for (int t = 0; t < 65; ++t) {
    int n0 = t * 32;
    int tlim = NTOK - n0; if (tlim > 32) tlim = 32;
    __syncthreads();
    {
      unsigned int pk[4];
#pragma unroll
      for (int j = 0; j < 8; ++j) {
        int n = n0 + tq * 8 + j; if (n >= NTOK) n = NTOK - 1;
        unsigned int v = kvb[(size_t)n * 1536 + 512 + dv];
        if (j & 1) pk[j >> 1] |= v << 16; else pk[j >> 1] = v;
      }
      *(uint2*)&VT[dv * 44 + tq * 8]     = make_uint2(pk[0], pk[1]);
      *(uint2*)&VT[dv * 44 + tq * 8 + 4] = make_uint2(pk[2], pk[3]);
    }
    bf16x8 aq[2][2];
    float dg[2];
#pragma unroll
    for (int mi = 0; mi < 2; ++mi) {
      int n = n0 + mi * 16 + m0; if (n >= NTOK) n = NTOK - 1;
      float s = 0.f;
#pragma unroll
      for (int ks = 0; ks < 2; ++ks) {
        aq[mi][ks] = *(const bf16x8*)(kvb + (size_t)n * 1536 + ks * 32 + kb * 8);
        const unsigned short* ap = (const unsigned short*)&aq[mi][ks];
#pragma unroll
        for (int j = 0; j < 8; ++j) { float v = b2f(ap[j]); s = fmaf(v, v, s); }
      }
      s += __shfl_xor(s, 16);
      s += __shfl_xor(s, 32);
      dg[mi] = 0.5f * DN * DN * s;
    }
    f32x4 da[2] = {};
#pragma unroll
    for (int ks = 0; ks < 2; ++ks)
#pragma unroll
      for (int mi = 0; mi < 2; ++mi)
        da[mi] = __builtin_amdgcn_mfma_f32_16x16x32_bf16(aq[mi][ks], bp[ks], da[mi], 0, 0, 0);
#pragma unroll
    for (int mi = 0; mi < 2; ++mi) {
      unsigned int pk[2];
#pragma unroll
      for (int r = 0; r < 4; ++r) {
        float dval = __shfl(dg[mi], (kb << 2) | r);
        int tt = mi * 16 + (kb << 2) + r;
        float kp = 0.f;
        if (tt < tlim)
          kp = RM * (__expf(da[mi][r] * DN - dval - kmax) + EPSK);
        ksum += kp;
        unsigned int h = (unsigned int)f2b(kp);
        if (r & 1) pk[r >> 1] |= h << 16; else pk[r >> 1] = h;
      }
      *(uint2*)&kpT[(w * 16 + m0) * 44 + mi * 16 + (kb << 2)] = make_uint2(pk[0], pk[1]);
    }
    __syncthreads();
    bf16x8 af = ld8s(&kpT[(w * 16 + m0) * 44 + kb * 8]);
#pragma unroll
    for (int di = 0; di < 4; ++di) {
      bf16x8 bfv = ld8s(&VT[(di * 16 + m0) * 44 + kb * 8]);
      acc[di] = __builtin_amdgcn_mfma_f32_16x16x32_bf16(af, bfv, acc[di], 0, 0, 0);
    }
  }
  ksum += __shfl_xor(ksum, 16);
  ksum += __shfl_xor(ksum, 32);
  if (kb == 0) kpsum[(size_t)bh * MM + mg * 64 + w * 16 + m0] = ksum;
  unsigned short* cT = ctxTb + (size_t)bh * (64 * 256);
#pragma unroll
  for (int di = 0; di < 4; ++di)
#pragma unroll
    for (int r = 0; r < 4; ++r) {
      int m = mg * 64 + w * 16 + (kb << 2) + r;
      int d = di * 16 + m0;
      cT[d * 256 + m] = f2b(acc[di][r]);
    }
}

// ====== FAVOR query pass (MFMA, KVQ: Q at cols 1024-1535, o -> cols 0-511) ======
__global__ __launch_bounds__(256) void qfeat_k(unsigned short* __restrict__ kv,
    const unsigned short* __restrict__ projb,
    const unsigned short* __restrict__ ctxTb,
    const float* __restrict__ kpsum) {
  int orig = blockIdx.y * gridDim.x + blockIdx.x;   // grid (256,13) = 3328
  int wg = ((orig & 7) * 416) + (orig >> 3);
  int bh = wg / 13, gy = wg % 13;
  int b = bh >> 3, hh = bh & 7;
  int tid = threadIdx.x;
  int lane = tid & 63, w = tid >> 6;
  int m0 = lane & 15, kb = lane >> 4;
  __shared__ float ddl[32 * 266];
  __shared__ unsigned short Pb[32 * 264];
  __shared__ float ksum_s[256];
  __shared__ float diag_s[32];
  __shared__ float dinv_s[32];
  ksum_s[tid] = kpsum[(size_t)bh * MM + tid];
  bf16x8 bp[4][2], bc[8];
#pragma unroll
  for (int nf = 0; nf < 4; ++nf)
#pragma unroll
    for (int ks = 0; ks < 2; ++ks)
      bp[nf][ks] = *(const bf16x8*)(projb + (size_t)(w * 64 + nf * 16 + m0) * 64 + ks * 32 + kb * 8);
  const unsigned short* cT = ctxTb + (size_t)bh * (64 * 256);
#pragma unroll
  for (int ks = 0; ks < 8; ++ks)
    bc[ks] = *(const bf16x8*)(cT + (size_t)(w * 16 + m0) * 256 + ks * 32 + kb * 8);
  unsigned short* kvb = kv + (size_t)b * NTOK * 1536 + hh * 64;
  int t8 = tid >> 3, q8 = tid & 7;
  for (int t = gy; t < 65; t += 13) {
    int n0 = t * 32;
    int tlim = NTOK - n0; if (tlim > 32) tlim = 32;
    bf16x8 aq[2][2];
#pragma unroll
    for (int mi = 0; mi < 2; ++mi) {
      int n = n0 + mi * 16 + m0; if (n >= NTOK) n = NTOK - 1;
#pragma unroll
      for (int ks = 0; ks < 2; ++ks)
        aq[mi][ks] = *(const bf16x8*)(kvb + (size_t)n * 1536 + 1024 + ks * 32 + kb * 8);
    }
#pragma unroll
    for (int mi = 0; mi < 2; ++mi) {
      float s = 0.f;
      const unsigned short* ap = (const unsigned short*)&aq[mi][0];
#pragma unroll
      for (int j = 0; j < 16; ++j) { float v = b2f(ap[j]); s = fmaf(v, v, s); }
      s += __shfl_xor(s, 16); s += __shfl_xor(s, 32);
      if (w == 0 && kb == 0) diag_s[mi * 16 + m0] = 0.5f * DN * DN * s;
    }
    f32x4 da[2][4] = {};
#pragma unroll
    for (int ks = 0; ks < 2; ++ks)
#pragma unroll
      for (int mi = 0; mi < 2; ++mi)
#pragma unroll
        for (int nf = 0; nf < 4; ++nf)
          da[mi][nf] = __builtin_amdgcn_mfma_f32_16x16x32_bf16(aq[mi][ks], bp[nf][ks], da[mi][nf], 0, 0, 0);
#pragma unroll
    for (int mi = 0; mi < 2; ++mi)
#pragma unroll
      for (int nf = 0; nf < 4; ++nf)
#pragma unroll
        for (int r = 0; r < 4; ++r)
          ddl[(mi * 16 + kb * 4 + r) * 266 + w * 64 + nf * 16 + m0] = da[mi][nf][r] * DN;
    __syncthreads();
    float mx = -1e30f;
    if (t8 < tlim) {
      for (int j = 0; j < 32; ++j) mx = fmaxf(mx, ddl[t8 * 266 + q8 + 8 * j]);
    }
    mx = fmaxf(mx, __shfl_xor(mx, 1));
    mx = fmaxf(mx, __shfl_xor(mx, 2));
    mx = fmaxf(mx, __shfl_xor(mx, 4));
    float den = 0.f;
    if (t8 < tlim) {
      float dg = diag_s[t8];
      for (int j = 0; j < 32; ++j) {
        int mm = q8 + 8 * j;
        float e = RM * (__expf(ddl[t8 * 266 + mm] - dg - mx) + EPSK);
        Pb[t8 * 264 + mm] = f2b(e);
        den = fmaf(e, ksum_s[mm], den);
      }
    }
    den += __shfl_xor(den, 1); den += __shfl_xor(den, 2); den += __shfl_xor(den, 4);
    if (q8 == 0 && t8 < tlim) dinv_s[t8] = 1.0f / den;
    __syncthreads();
    f32x4 oa[2] = {};
#pragma unroll
    for (int ks = 0; ks < 8; ++ks)
#pragma unroll
      for (int mi = 0; mi < 2; ++mi) {
        bf16x8 ap = *(const bf16x8*)&Pb[(mi * 16 + m0) * 264 + ks * 32 + kb * 8];
        oa[mi] = __builtin_amdgcn_mfma_f32_16x16x32_bf16(ap, bc[ks], oa[mi], 0, 0, 0);
      }
#pragma unroll
    for (int mi = 0; mi < 2; ++mi)
#pragma unroll
      for (int r = 0; r < 4; ++r) {
        int row = mi * 16 + kb * 4 + r;
        if (row < tlim) {
          kvb[(size_t)(n0 + row) * 1536 + w * 16 + m0] =
              f2b(oa[mi][r] * dinv_s[row]);
        }
      }
    __syncthreads();
  }
}

// ======= final cross-attention, 4-phase parallel (packed kc|vc, stride 1024) =======
__global__ __launch_bounds__(256) void attn_sc_k(const unsigned short* __restrict__ qc,
    const unsigned short* __restrict__ kcvc, float* __restrict__ scbuf,
    float* __restrict__ pmax) {
  int b = blockIdx.x, g = blockIdx.y, tid = threadIdx.x;
  int w = tid >> 6, lane = tid & 63;
  __shared__ float qs[DD];
  __shared__ float red[4];
  {
    ushort2 qu = ((const ushort2*)(qc + (size_t)b * DD))[tid];
    ((float2*)qs)[tid] = make_float2(b2f(qu.x), b2f(qu.y));
  }
  __syncthreads();
  float mx = -1e30f;
  for (int it = 0; it < 64; ++it) {
    int kk = g * 256 + w * 64 + it;
    const unsigned short* row = kcvc + ((size_t)b * NTOK + 1 + kk) * 1024 + lane * 8;
    float4 r0 = ld4(row), r1 = ld4(row + 4);
    float4 q0 = ((const float4*)qs)[lane * 2], q1 = ((const float4*)qs)[lane * 2 + 1];
    float s = r0.x * q0.x + r0.y * q0.y + r0.z * q0.z + r0.w * q0.w
            + r1.x * q1.x + r1.y * q1.y + r1.z * q1.z + r1.w * q1.w;
    s = wsum(s) * 0.044194173824159216f; // 1/sqrt(512)
    if (lane == 0) scbuf[(size_t)b * KK + kk] = s;
    mx = fmaxf(mx, s);
  }
  if (lane == 0) red[w] = mx;
  __syncthreads();
  if (tid == 0) pmax[b * 8 + g] = fmaxf(fmaxf(red[0], red[1]), fmaxf(red[2], red[3]));
}
__global__ __launch_bounds__(256) void attn_w_k(const float* __restrict__ pmax,
    float* __restrict__ scbuf, float* __restrict__ pinv) {
  int b = blockIdx.x, tid = threadIdx.x;
  __shared__ float red[4];
  float mx = -1e30f;
#pragma unroll
  for (int i = 0; i < 8; ++i) mx = fmaxf(mx, pmax[b * 8 + i]);
  float sum = 0.f;
  for (int i = tid; i < KK; i += 256) {
    float e = __expf(scbuf[(size_t)b * KK + i] - mx);
    scbuf[(size_t)b * KK + i] = e;
    sum += e;
  }
  sum = wsum(sum);
  if ((tid & 63) == 0) red[tid >> 6] = sum;
  __syncthreads();
  if (tid == 0) pinv[b] = 1.0f / (red[0] + red[1] + red[2] + red[3]);
}
__global__ __launch_bounds__(256) void attn_vs_k(const float* __restrict__ scbuf,
    const unsigned short* __restrict__ kcvc, float* __restrict__ ppart) {
  int b = blockIdx.x, g = blockIdx.y, tid = threadIdx.x;
  float2 acc = {0.f, 0.f};
  for (int it = 0; it < 256; ++it) {
    int kk = g * 256 + it;
    float wgt = scbuf[(size_t)b * KK + kk];
    ushort2 vu = ((const ushort2*)(kcvc + ((size_t)b * NTOK + 1 + kk) * 1024 + 512))[tid];
    acc.x = fmaf(wgt, b2f(vu.x), acc.x);
    acc.y = fmaf(wgt, b2f(vu.y), acc.y);
  }
  ((float2*)(ppart + ((size_t)b * 8 + g) * DD))[tid] = acc;
}
__global__ __launch_bounds__(256) void attn_red_k(const float* __restrict__ ppart,
    const float* __restrict__ pinv, float* __restrict__ pooled) {
  int b = blockIdx.x, tid = threadIdx.x;
  float inv = pinv[b];
  float2 acc = {0.f, 0.f};
#pragma unroll
  for (int g = 0; g < 8; ++g) {
    float2 p = ((const float2*)(ppart + ((size_t)b * 8 + g) * DD))[tid];
    acc.x += p.x; acc.y += p.y;
  }
  ((float2*)(pooled + (size_t)b * DD))[tid] = make_float2(acc.x * inv, acc.y * inv);
}

// ---------------- final projection, fp32 out ----------------
__global__ __launch_bounds__(256) void out_k(const float* __restrict__ pooled,
    const float* __restrict__ co_w, const float* __restrict__ co_b,
    float* __restrict__ out) {
  int b = blockIdx.x, tid = threadIdx.x;
  __shared__ float ps[DD];
  ((float2*)ps)[tid] = ((const float2*)(pooled + (size_t)b * DD))[tid];
  __syncthreads();
  float a0 = co_b[tid], a1 = co_b[tid + 256];
  for (int d = 0; d < 512; ++d) {
    float p = ps[d];
    a0 = fmaf(p, co_w[(size_t)d * 512 + tid], a0);
    a1 = fmaf(p, co_w[(size_t)d * 512 + tid + 256], a1);
  }
  out[(size_t)b * 512 + tid] = a0;
  out[(size_t)b * 512 + tid + 256] = a1;
}

extern "C" void kernel_launch(void* const* d_in, const int* in_sizes, int n_in,
                              void* d_out, int out_size, void* d_ws, size_t ws_size,
                              hipStream_t stream) {
  const float* expr       = (const float*)d_in[0];
  const float* coords     = (const float*)d_in[1];
  const int*   gene_ids   = (const int*)d_in[2];
  const float* gene_table = (const float*)d_in[3];
  const float* pos_table  = (const float*)d_in[4];
  const float* value_tab  = (const float*)d_in[5];
  const float* sp_w  = (const float*)d_in[6];
  const float* sp_b  = (const float*)d_in[7];
  const float* sp_g  = (const float*)d_in[8];
  const float* sp_bb = (const float*)d_in[9];
  const float* ln1_g = (const float*)d_in[10];
  const float* ln1_b = (const float*)d_in[11];
  const float* qw = (const float*)d_in[12];
  const float* qbias = (const float*)d_in[13];
  const float* kw = (const float*)d_in[14];
  const float* kbias = (const float*)d_in[15];
  const float* vw = (const float*)d_in[16];
  const float* vbias = (const float*)d_in[17];
  const float* ow = (const float*)d_in[18];
  const float* obias = (const float*)d_in[19];
  const float* proj  = (const float*)d_in[20];
  const float* ln2_g = (const float*)d_in[21];
  const float* ln2_b = (const float*)d_in[22];
  const float* ff1w = (const float*)d_in[23];
  const float* ff1b = (const float*)d_in[24];
  const float* ff2w = (const float*)d_in[25];
  const float* ff2b = (const float*)d_in[26];
  const float* cqw = (const float*)d_in[27];
  const float* cqb = (const float*)d_in[28];
  const float* ckw = (const float*)d_in[29];
  const float* ckb = (const float*)d_in[30];
  const float* cvw = (const float*)d_in[31];
  const float* cvb = (const float*)d_in[32];
  const float* cow = (const float*)d_in[33];
  const float* cob = (const float*)d_in[34];
  float* out = (float*)d_out;

  const size_t SZ = (size_t)RTOT * DD;
  const size_t MS = (size_t)DD * DD;
  const size_t FS = (size_t)DD * 4 * DD;
  const size_t LST = 4 * MS + 2 * FS;
  const size_t WBN = 4 * LST + 2 * MS;
  const size_t CTXN = (size_t)BB * NH * 64 * 256;
  const size_t KVQN = (size_t)RTOT * 1536;

  unsigned short* x = (unsigned short*)d_ws;       // bf16 residual, SZ
  unsigned short* KVQb = x + SZ;                   // K|V|Q packed [row][1536] -> o|mid
  unsigned short* Cb = KVQb + KVQN;                // LN output, SZ
  unsigned short* wb = Cb + SZ;
  unsigned short* ctxTb = wb + WBN;
  unsigned short* projb = ctxTb + CTXN;
  float* kpsum = (float*)(projb + (size_t)NL * MM * DHD);
  float* pooled = kpsum + (size_t)BB * NH * MM;
  float* bmax  = pooled + (size_t)BB * DD;
  float* kmaxg = bmax + 2816;
  float* scbuf = kmaxg + 16;
  float* pmax  = scbuf + (size_t)BB * KK;
  float* pinv  = pmax + 256;
  float* ppart = pinv + 32;
  float* biasKVQ = ppart + (size_t)BB * 8 * DD;    // NL*1536 + 1024
  unsigned short* qcb = (unsigned short*)(biasKVQ + (size_t)NL * 1536 + 1024);
  size_t need = (size_t)((char*)(qcb + (size_t)BB * DD) - (char*)d_ws) + 256;
  if (ws_size < need) {
    sentinel_k<<<(out_size + 255) / 256, 256, 0, stream>>>(out, out_size);
    return;
  }

  for (int l = 0; l < NL; ++l) {
    unsigned short* wl = wb + l * LST;
    wcvt_k<<<dim3(8, 8), 256, 0, stream>>>(kw + l * MS, wl,          512, 512);
    wcvt_k<<<dim3(8, 8), 256, 0, stream>>>(vw + l * MS, wl + MS,     512, 512);
    wcvt_k<<<dim3(8, 8), 256, 0, stream>>>(qw + l * MS, wl + 2 * MS, 512, 512);
    wcvt_k<<<dim3(8, 8), 256, 0, stream>>>(ow + l * MS, wl + 3 * MS, 512, 512);
    wcvt_k<<<dim3(32, 8), 256, 0, stream>>>(ff1w + l * FS, wl + 4 * MS,      512, 2048);
    wcvt_k<<<dim3(8, 32), 256, 0, stream>>>(ff2w + l * FS, wl + 4 * MS + FS, 2048, 512);
    biaspack3_k<<<1, 256, 0, stream>>>(kbias + l * DD, vbias + l * DD, qbias + l * DD,
                                       biasKVQ + l * 1536);
  }
  wcvt_k<<<dim3(8, 8), 256, 0, stream>>>(ckw, wb + 4 * LST,      512, 512);
  wcvt_k<<<dim3(8, 8), 256, 0, stream>>>(cvw, wb + 4 * LST + MS, 512, 512);
  biaspack_k<<<1, 256, 0, stream>>>(ckb, cvb, biasKVQ + NL * 1536);
  {  // proj -> bf16
    const float* p4 = proj;
    unsigned short* pb = projb;
    // reuse cvt via small inline kernel-free path: use wcvt? proj is [256][64] row-major
    // simple: convert with a dedicated launch of the generic converter below
    (void)p4; (void)pb;
  }
  // proj fp32 -> bf16 (contiguous)
  {
    struct Cvt { };
  }
  // use a tiny lambda-style kernel: reuse ln-style conversion via cvtp_k below
  extern __global__ void cvtp_k(const float*, unsigned short*, size_t);
  cvtp_k<<<32, 256, 0, stream>>>(proj, projb, (size_t)NL * MM * DHD / 8);

  embed_k<<<BB * KK / 2, 256, 0, stream>>>(expr, gene_ids, gene_table, pos_table, value_tab, x);
  sp_k<<<BB, 256, 0, stream>>>(coords, sp_w, sp_b, sp_g, sp_bb, x);

  const int RB = (RTOT + 127) / 128;   // 513
  const int HB = (HROWS + 127) / 128;  // 257
  for (int l = 0; l < NL; ++l) {
    unsigned short* wl = wb + l * LST;
    const unsigned short* pbl = projb + (size_t)l * MM * DHD;
    ln_k<<<RTOT, 128, 0, stream>>>(x, ln1_g + l * DD, ln1_b + l * DD, Cb);
    // fused K|V|Q GEMM -> KVQb [row][1536]
    gemm_bb<unsigned short, 0><<<dim3(12, RB), 256, 0, stream>>>(Cb, DD,
        wl, biasKVQ + l * 1536, KVQb, 1536, RTOT, DD);
    kmax_k<<<dim3(256, 4), 256, 0, stream>>>(KVQb, pbl, bmax);
    maxred_k<<<1, 256, 0, stream>>>(bmax, BB * NH * 4, kmaxg);
    k2_k<<<dim3(256, 4), 256, 0, stream>>>(KVQb, pbl, kmaxg, ctxTb, kpsum);
    qfeat_k<<<dim3(256, 13), 256, 0, stream>>>(KVQb, pbl, ctxTb, kpsum);  // o -> cols 0-511
    gemm_bb<unsigned short, 2><<<dim3(4, RB), 256, 0, stream>>>(KVQb, 1536,
        wl + 3 * MS, obias + l * DD, x, DD, RTOT, DD);
    ln_k<<<RTOT, 128, 0, stream>>>(x, ln2_g + l * DD, ln2_b + l * DD, Cb);
    for (int c = 0; c < 2; ++c) {
      gemm_bb<unsigned short, 1><<<dim3(16, HB), 256, 0, stream>>>(Cb + (size_t)c * HROWS * DD, DD,
          wl + 4 * MS, ff1b + (size_t)l * 4 * DD, KVQb, 2048, HROWS, DD);
      gemm_bb<unsigned short, 2><<<dim3(4, HB), 256, 0, stream>>>(KVQb, 2048,
          wl + 4 * MS + FS, ff2b + l * DD, x + (size_t)c * HROWS * DD, DD, HROWS, 2048);
    }
  }
  // fused kc|vc from bf16 x directly -> KVQb [row][1024]
  gemm_bb<unsigned short, 0><<<dim3(8, RB), 256, 0, stream>>>(x, DD,
      wb + 4 * LST, biasKVQ + NL * 1536, KVQb, 1024, RTOT, DD);
  gemm_t<unsigned short, unsigned short><<<dim3(8, 1), 256, 0, stream>>>(x, (long)NTOK * DD,
      cqw, cqb, qcb, DD, BB, DD, DD);
  attn_sc_k<<<dim3(BB, 8), 256, 0, stream>>>(qcb, KVQb, scbuf, pmax);
  attn_w_k<<<BB, 256, 0, stream>>>(pmax, scbuf, pinv);
  attn_vs_k<<<dim3(BB, 8), 256, 0, stream>>>(scbuf, KVQb, ppart);
  attn_red_k<<<BB, 256, 0, stream>>>(ppart, pinv, pooled);
  out_k<<<BB, 256, 0, stream>>>(pooled, cow, cob, out);
}

// ---------------- fp32 -> bf16 contiguous converter (proj) ----------------
__global__ __launch_bounds__(256) void cvtp_k(const float* __restrict__ src,
    unsigned short* __restrict__ dst, size_t n8) {
  size_t i = (size_t)blockIdx.x * 256 + threadIdx.x;
  if (i >= n8) return;
  float4 a = ((const float4*)src)[2 * i];
  float4 b = ((const float4*)src)[2 * i + 1];
  st4(dst + i * 8, a);
  st4(dst + i * 8 + 4, b);
}